// Round 15
// baseline (106.098 us; speedup 1.0000x reference)
//
#include <hip/hip_runtime.h>

// DPQ network:
//  k_score : response argmax via FULL-split bf16 MFMA ((ah+al)(bh+bl));
//            areg[8] + software-pipelined prefetch (5 waves/SIMD);
//            cvt_pk B-prep; med3 pair tracking; CERT=0.004 + inline rescue
//  k_gemm  : codebook-gather GEMM (bf16 MFMA); y==0 blocks also emit
//            negout/codefout (k_finish folded in)
// B=32768, C=32, K=256, D_SUB=16, D_IN=512, D_OUT=512

#define NB 32768
#define NC 32
#define NK 256
#define NDS 16
#define NDIN 512
#define NDOUT 512
#define CERT 0.004f

typedef __attribute__((ext_vector_type(8))) short s8v;          // 8 bf16
typedef __attribute__((ext_vector_type(4))) float f4v;          // MFMA acc
typedef __attribute__((ext_vector_type(4))) unsigned int u4v;   // 4 u32 = 8 bf16

__device__ __forceinline__ unsigned short f2bf(float f) {
  unsigned int u = __float_as_uint(f);
  u += 0x7fffu + ((u >> 16) & 1u);   // RNE
  return (unsigned short)(u >> 16);
}
__device__ __forceinline__ float bf2f(unsigned short h) {
  return __uint_as_float(((unsigned int)h) << 16);
}

// packed f32->bf16 (RNE), 2 values per instruction
#define CVTPK(d, lo, hi) \
  asm("v_cvt_pk_bf16_f32 %0, %1, %2" : "=v"(d) : "v"(lo), "v"(hi))

__device__ __forceinline__ void gload16(const void* g, void* l) {
  __builtin_amdgcn_global_load_lds(
      (const __attribute__((address_space(1))) void*)g,
      (__attribute__((address_space(3))) void*)l, 16, 0, 0);
}

// exact f32 dot over 16 dims, sequential fold (same association everywhere)
__device__ __forceinline__ float dot16(const float* x, const float* cj) {
  float4 a0 = *(const float4*)(x + 0),  a1 = *(const float4*)(x + 4);
  float4 a2 = *(const float4*)(x + 8),  a3 = *(const float4*)(x + 12);
  float4 c0 = *(const float4*)(cj + 0), c1 = *(const float4*)(cj + 4);
  float4 c2 = *(const float4*)(cj + 8), c3 = *(const float4*)(cj + 12);
  float s = a0.x * c0.x;
  s = fmaf(a0.y, c0.y, s); s = fmaf(a0.z, c0.z, s); s = fmaf(a0.w, c0.w, s);
  s = fmaf(a1.x, c1.x, s); s = fmaf(a1.y, c1.y, s); s = fmaf(a1.z, c1.z, s); s = fmaf(a1.w, c1.w, s);
  s = fmaf(a2.x, c2.x, s); s = fmaf(a2.y, c2.y, s); s = fmaf(a2.z, c2.z, s); s = fmaf(a2.w, c2.w, s);
  s = fmaf(a3.x, c3.x, s); s = fmaf(a3.y, c3.y, s); s = fmaf(a3.z, c3.z, s); s = fmaf(a3.w, c3.w, s);
  return s;
}

// ---------------------------------------------------------------------------
// Kernel 0: Wt[n][k] = bf16(W[k][n]); centsH = flat bf16 (gemm gather source);
//           centsP4[c][plane][k][8]: plane 0 hi d0-7, 1 hi d8-15, 2 lo d0-7,
//           3 lo d8-15 (A-fragment order)
// ---------------------------------------------------------------------------
__global__ __launch_bounds__(256) void k_prep(const float* __restrict__ W,
                                              const float* __restrict__ cents,
                                              unsigned short* __restrict__ Wt,
                                              unsigned short* __restrict__ centsH,
                                              unsigned short* __restrict__ centsP4) {
  const int t = threadIdx.x;
  const int bid = blockIdx.x;
  if (bid < 256) {
    __shared__ float tile[32][33];
    const int k0 = (bid >> 4) << 5;
    const int n0 = (bid & 15) << 5;
    const int tx = t & 31, ty = t >> 5;
#pragma unroll
    for (int i = 0; i < 4; ++i) {
      int r = ty + i * 8;
      tile[r][tx] = W[(size_t)(k0 + r) * NDOUT + n0 + tx];
    }
    __syncthreads();
#pragma unroll
    for (int i = 0; i < 4; ++i) {
      int r = ty + i * 8;
      Wt[(size_t)(n0 + r) * NDIN + k0 + tx] = f2bf(tile[tx][r]);
    }
  } else {
    // per-c codebook processing: c = bid-256, thread t = k
    const int c = bid - 256;
    const int k = t;
    const float* src = cents + ((size_t)c * NK + k) * NDS;
    unsigned short hi[16], lo[16];
#pragma unroll
    for (int j = 0; j < 4; ++j) {
      float4 v = *(const float4*)(src + j * 4);
      unsigned short h0 = f2bf(v.x), h1 = f2bf(v.y), h2 = f2bf(v.z), h3 = f2bf(v.w);
      hi[j * 4 + 0] = h0; hi[j * 4 + 1] = h1; hi[j * 4 + 2] = h2; hi[j * 4 + 3] = h3;
      lo[j * 4 + 0] = f2bf(v.x - bf2f(h0));
      lo[j * 4 + 1] = f2bf(v.y - bf2f(h1));
      lo[j * 4 + 2] = f2bf(v.z - bf2f(h2));
      lo[j * 4 + 3] = f2bf(v.w - bf2f(h3));
    }
    unsigned short* hf = centsH + ((size_t)c * NK + k) * NDS;
#pragma unroll
    for (int j = 0; j < 4; ++j)
      *(ushort4*)(hf + j * 4) = make_ushort4(hi[j * 4], hi[j * 4 + 1], hi[j * 4 + 2], hi[j * 4 + 3]);
    unsigned short* pb = centsP4 + (size_t)c * 8192 + k * 8;
    *(ushort4*)(pb + 0 * 2048 + 0) = make_ushort4(hi[0], hi[1], hi[2], hi[3]);
    *(ushort4*)(pb + 0 * 2048 + 4) = make_ushort4(hi[4], hi[5], hi[6], hi[7]);
    *(ushort4*)(pb + 1 * 2048 + 0) = make_ushort4(hi[8], hi[9], hi[10], hi[11]);
    *(ushort4*)(pb + 1 * 2048 + 4) = make_ushort4(hi[12], hi[13], hi[14], hi[15]);
    *(ushort4*)(pb + 2 * 2048 + 0) = make_ushort4(lo[0], lo[1], lo[2], lo[3]);
    *(ushort4*)(pb + 2 * 2048 + 4) = make_ushort4(lo[4], lo[5], lo[6], lo[7]);
    *(ushort4*)(pb + 3 * 2048 + 0) = make_ushort4(lo[8], lo[9], lo[10], lo[11]);
    *(ushort4*)(pb + 3 * 2048 + 4) = make_ushort4(lo[12], lo[13], lo[14], lo[15]);
  }
}

// build hi-packed s8v + residuals from 8 f32 (u0,u1)
__device__ __forceinline__ void split8(float4 u0, float4 u1, s8v& bh, s8v& bl) {
  unsigned int ph0, ph1, ph2, ph3;
  CVTPK(ph0, u0.x, u0.y); CVTPK(ph1, u0.z, u0.w);
  CVTPK(ph2, u1.x, u1.y); CVTPK(ph3, u1.z, u1.w);
  bh = __builtin_bit_cast(s8v, (u4v){ph0, ph1, ph2, ph3});
  float ra = u0.x - __uint_as_float(ph0 << 16);
  float rb = u0.y - __uint_as_float(ph0 & 0xFFFF0000u);
  float rc = u0.z - __uint_as_float(ph1 << 16);
  float rd = u0.w - __uint_as_float(ph1 & 0xFFFF0000u);
  float re = u1.x - __uint_as_float(ph2 << 16);
  float rf = u1.y - __uint_as_float(ph2 & 0xFFFF0000u);
  float rg = u1.z - __uint_as_float(ph3 << 16);
  float rh = u1.w - __uint_as_float(ph3 & 0xFFFF0000u);
  unsigned int pl0, pl1, pl2, pl3;
  CVTPK(pl0, ra, rb); CVTPK(pl1, rc, rd);
  CVTPK(pl2, re, rf); CVTPK(pl3, rg, rh);
  bl = __builtin_bit_cast(s8v, (u4v){pl0, pl1, pl2, pl3});
}

// track a pair of adjacent-k scores (kc0, kc0+1): ~8 VALU ops / 2 scores.
#define TRACK2(v0, v1, kc0, best, sec, bk)                     \
  {                                                            \
    float vm_ = fmaxf(v0, v1);                                 \
    float md_ = __builtin_amdgcn_fmed3f(best, v0, v1);         \
    sec = fmaxf(sec, md_);                                     \
    int km_ = (v1 > v0) ? (kc0 + 1) : (kc0);                   \
    bool gt_ = vm_ > best;                                     \
    bk = gt_ ? km_ : bk;                                       \
    best = fmaxf(best, vm_);                                   \
  }

// ---------------------------------------------------------------------------
// k_score: per wave = 32 b's x 1 c. areg[8] + software-pipelined prefetch
// (first-half iterations prefetch kt+8 after use; all indices static).
// FULL-split pairing: A = [ah|al] by lane, pass1 B = [bh|bl], pass2 B =
// [bl|bh] => acc = (ah+al)(bh+bl). Tracking/butterfly/finalize/rescue
// verbatim from passing R14.
// ---------------------------------------------------------------------------
__global__ __launch_bounds__(256, 5) void k_score(const float* __restrict__ inputs,
                                                  const unsigned short* __restrict__ centsP4,
                                                  const float* __restrict__ cents,
                                                  float* __restrict__ T_neg,
                                                  int* __restrict__ T_code) {
  const int t = threadIdx.x;
  const int l = t & 63;
  const int w = t >> 6;
  const int c = blockIdx.y;
  const int b0 = blockIdx.x * 128 + w * 32;   // this wave: b0..b0+31 (two 16-col subtiles)
  const int g = l >> 4;
  const int col = l & 15;
  const int dh = (g & 1) * 8;
  const int g4 = g * 4;

  // ---- first 8 A-fragments (independent 16B loads)
  const unsigned short* abase = centsP4 + (size_t)c * 8192 + g * 2048 + col * 8;
  s8v areg[8];
#pragma unroll
  for (int kt = 0; kt < 8; ++kt)
    areg[kt] = *(const s8v*)(abase + kt * 128);

  // ---- B fragments (two subtiles), hi/lo split via cvt_pk; full-split pairing
  s8v p1f0, p2f0, p1f1, p2f1;
  {
    const float* r0 = inputs + ((size_t)(b0 + col) * NC + c) * NDS + dh;
    const float* r1 = inputs + ((size_t)(b0 + 16 + col) * NC + c) * NDS + dh;
    float4 u0 = *(const float4*)(r0), u1 = *(const float4*)(r0 + 4);
    float4 v0 = *(const float4*)(r1), v1 = *(const float4*)(r1 + 4);
    s8v bh0, bl0, bh1, bl1;
    split8(u0, u1, bh0, bl0);
    split8(v0, v1, bh1, bl1);
    const bool hiLane = (l < 32);             // kappa 0-15 lanes
    p1f0 = hiLane ? bh0 : bl0;                // pass1: [bh | bl]
    p2f0 = hiLane ? bl0 : bh0;                // pass2: [bl | bh]
    p1f1 = hiLane ? bh1 : bl1;
    p2f1 = hiLane ? bl1 : bh1;
  }

  float best0 = -3.0e38f, sec0 = -3.0e38f;
  float best1 = -3.0e38f, sec1 = -3.0e38f;
  int bk0 = 0, bk1 = 0;
  const f4v zz = {0.0f, 0.0f, 0.0f, 0.0f};

#pragma unroll
  for (int kt = 0; kt < 8; ++kt) {
    s8v a = areg[kt];
    areg[kt] = *(const s8v*)(abase + (kt + 8) * 128);   // prefetch kt+8 (hidden)
    f4v acc0 = __builtin_amdgcn_mfma_f32_16x16x32_bf16(a, p1f0, zz, 0, 0, 0);
    acc0 = __builtin_amdgcn_mfma_f32_16x16x32_bf16(a, p2f0, acc0, 0, 0, 0);
    f4v acc1 = __builtin_amdgcn_mfma_f32_16x16x32_bf16(a, p1f1, zz, 0, 0, 0);
    acc1 = __builtin_amdgcn_mfma_f32_16x16x32_bf16(a, p2f1, acc1, 0, 0, 0);
    const int kc = kt * 16;
    TRACK2(acc0[0], acc0[1], kc + 0, best0, sec0, bk0)
    TRACK2(acc0[2], acc0[3], kc + 2, best0, sec0, bk0)
    TRACK2(acc1[0], acc1[1], kc + 0, best1, sec1, bk1)
    TRACK2(acc1[2], acc1[3], kc + 2, best1, sec1, bk1)
  }

#pragma unroll
  for (int kt = 8; kt < 16; ++kt) {
    s8v a = areg[kt - 8];
    f4v acc0 = __builtin_amdgcn_mfma_f32_16x16x32_bf16(a, p1f0, zz, 0, 0, 0);
    acc0 = __builtin_amdgcn_mfma_f32_16x16x32_bf16(a, p2f0, acc0, 0, 0, 0);
    f4v acc1 = __builtin_amdgcn_mfma_f32_16x16x32_bf16(a, p1f1, zz, 0, 0, 0);
    acc1 = __builtin_amdgcn_mfma_f32_16x16x32_bf16(a, p2f1, acc1, 0, 0, 0);
    const int kc = kt * 16;
    TRACK2(acc0[0], acc0[1], kc + 0, best0, sec0, bk0)
    TRACK2(acc0[2], acc0[3], kc + 2, best0, sec0, bk0)
    TRACK2(acc1[0], acc1[1], kc + 0, best1, sec1, bk1)
    TRACK2(acc1[2], acc1[3], kc + 2, best1, sec1, bk1)
  }

  bk0 += g4;
  bk1 += g4;

  // butterfly across the 4 lane-groups (verbatim)
#pragma unroll
  for (int off = 16; off <= 32; off <<= 1) {
    float vb = __shfl_xor(best0, off);
    float sb = __shfl_xor(sec0, off);
    int kb = __shfl_xor(bk0, off);
    float mn = fminf(best0, vb);
    sec0 = fmaxf(fmaxf(sec0, sb), mn);
    bool take = (vb > best0) || (vb == best0 && kb < bk0);
    bk0 = take ? kb : bk0;
    best0 = fmaxf(best0, vb);

    vb = __shfl_xor(best1, off);
    sb = __shfl_xor(sec1, off);
    kb = __shfl_xor(bk1, off);
    mn = fminf(best1, vb);
    sec1 = fmaxf(fmaxf(sec1, sb), mn);
    take = (vb > best1) || (vb == best1 && kb < bk1);
    bk1 = take ? kb : bk1;
    best1 = fmaxf(best1, vb);
  }

  // per-result-lane final values (lanes 0..31 own b = b0 + l)
  const int sub = (l >> 4) & 1;
  float best = sub ? best1 : best0;
  float sec = sub ? sec1 : sec0;
  int bk = sub ? bk1 : bk0;
  const bool owner = (l < 32);
  const bool flagged = owner && (best - sec <= CERT);

  if (owner && !flagged) {
    const int b = b0 + l;
    const float* xr = inputs + ((size_t)b * NC + c) * NDS;
    const float* cr = cents + ((size_t)c * NK + bk) * NDS;
    size_t o = (size_t)c * NB + b;
    T_neg[o] = dot16(xr, cr);
    T_code[o] = bk;
  }

  // inline rescue: whole wave rescans flagged entries exactly (verbatim)
  unsigned long long mask = __ballot(flagged);
  while (mask) {
    const int p = __builtin_ctzll(mask);
    mask &= mask - 1;
    const int b = b0 + p;
    const float* xr = inputs + ((size_t)b * NC + c) * NDS;
    const float* cr = cents + ((size_t)c * NK + l * 4) * NDS;
    float rb = -3.0e38f;
    int rk = 0;
#pragma unroll
    for (int q = 0; q < 4; ++q) {
      float d = dot16(xr, cr + q * NDS);
      if (d > rb) { rb = d; rk = l * 4 + q; }   // strict >, ascending k
    }
#pragma unroll
    for (int off = 1; off <= 32; off <<= 1) {
      float vb = __shfl_xor(rb, off);
      int kb = __shfl_xor(rk, off);
      bool take = (vb > rb) || (vb == rb && kb < rk);
      rb = take ? vb : rb;
      rk = take ? kb : rk;
    }
    if (l == 0) {
      size_t o = (size_t)c * NB + b;
      T_neg[o] = rb;
      T_code[o] = rk;
    }
  }
}

// ---------------------------------------------------------------------------
// Kernel 2: product = gather(centsH, codes) @ W  via bf16 MFMA.
// Codes read from T_code[c][b]. blockIdx.y==0 blocks also emit negout and
// codefout for their 128 rows (k_finish folded in; As reused as staging).
// ---------------------------------------------------------------------------
__global__ __launch_bounds__(256) void k_gemm(const unsigned short* __restrict__ centsB,
                                              const int* __restrict__ T_code,
                                              const float* __restrict__ T_neg,
                                              const unsigned short* __restrict__ Wt,
                                              float* __restrict__ out,
                                              float* __restrict__ negout,
                                              float* __restrict__ codefout) {
  __shared__ __align__(16) unsigned short As[128 * 64];
  __shared__ __align__(16) unsigned short Bs[128 * 64];
  __shared__ int lcode[128 * 33];

  const int t = threadIdx.x;
  const int l = t & 63;
  const int w = t >> 6;
  const int wm = w >> 1, wn = w & 1;
  const int m0 = blockIdx.x * 128;
  const int n0 = blockIdx.y * 128;

  {
    // lcode[row][col] = T_code[col*NB + m0 + row]
    const int cc = t >> 3;          // 0..31
    const int ch = t & 7;           // 0..7 -> rows ch*16..ch*16+15
#pragma unroll
    for (int i = 0; i < 4; ++i) {
      int row0 = ch * 16 + i * 4;
      int4 v = *(const int4*)(T_code + (size_t)cc * NB + m0 + row0);
      lcode[(row0 + 0) * 33 + cc] = v.x;
      lcode[(row0 + 1) * 33 + cc] = v.y;
      lcode[(row0 + 2) * 33 + cc] = v.z;
      lcode[(row0 + 3) * 33 + cc] = v.w;
    }
  }

  f4v acc[4][4] = {};
  const int s = t & 7;
  const int rq = t >> 3;

  for (int kt = 0; kt < 8; ++kt) {
    __syncthreads();
    const int c0 = kt * 4;
#pragma unroll
    for (int i = 0; i < 4; ++i) {
      int lr = i * 32 + rq;
      int srcslot = s ^ (lr & 7);
      int cl = srcslot >> 1, half = srcslot & 1;
      int code = lcode[lr * 33 + c0 + cl];
      const unsigned short* gsrc =
          centsB + ((size_t)((c0 + cl) * NK + code) * NDS + half * 8);
      gload16(gsrc, (char*)As + i * 4096 + (w << 10));
    }
#pragma unroll
    for (int i = 0; i < 4; ++i) {
      int lr = i * 32 + rq;
      int k16 = s ^ (lr & 7);
      const unsigned short* gsrc = Wt + (size_t)(n0 + lr) * NDIN + kt * 64 + k16 * 8;
      gload16(gsrc, (char*)Bs + i * 4096 + (w << 10));
    }
    __syncthreads();

    s8v af[4][2], bfr[4][2];
#pragma unroll
    for (int mf = 0; mf < 4; ++mf)
#pragma unroll
      for (int ks = 0; ks < 2; ++ks) {
        int row = wm * 64 + mf * 16 + (l & 15);
        int slot = ks * 4 + (l >> 4);
        af[mf][ks] = *(const s8v*)((const char*)As + row * 128 + ((slot ^ (row & 7)) << 4));
      }
#pragma unroll
    for (int nf = 0; nf < 4; ++nf)
#pragma unroll
      for (int ks = 0; ks < 2; ++ks) {
        int row = wn * 64 + nf * 16 + (l & 15);
        int slot = ks * 4 + (l >> 4);
        bfr[nf][ks] = *(const s8v*)((const char*)Bs + row * 128 + ((slot ^ (row & 7)) << 4));
      }
#pragma unroll
    for (int ks = 0; ks < 2; ++ks)
#pragma unroll
      for (int mf = 0; mf < 4; ++mf)
#pragma unroll
        for (int nf = 0; nf < 4; ++nf)
          acc[mf][nf] = __builtin_amdgcn_mfma_f32_16x16x32_bf16(
              af[mf][ks], bfr[nf][ks], acc[mf][nf], 0, 0, 0);
  }

#pragma unroll
  for (int mf = 0; mf < 4; ++mf)
#pragma unroll
    for (int nf = 0; nf < 4; ++nf)
#pragma unroll
      for (int r = 0; r < 4; ++r) {
        int row = m0 + wm * 64 + mf * 16 + (l >> 4) * 4 + r;
        int col = n0 + wn * 64 + nf * 16 + (l & 15);
        out[(size_t)row * NDOUT + col] = acc[mf][nf][r];
      }

  // ---- folded k_finish: y==0 blocks emit negout/codefout for rows m0..m0+127
  if (blockIdx.y == 0) {
    __syncthreads();                 // all frag reads of As done; safe to reuse
    float* sf = (float*)As;          // 4096 floats = 128 b x 32 c staging
    {
      const int cc = t >> 3;         // 0..31
      const int ch = t & 7;          // 0..7
#pragma unroll
      for (int i = 0; i < 4; ++i) {
        int row0 = ch * 16 + i * 4;
        float4 v = *(const float4*)(T_neg + (size_t)cc * NB + m0 + row0);
        sf[(row0 + 0) * 32 + cc] = v.x;
        sf[(row0 + 1) * 32 + cc] = v.y;
        sf[(row0 + 2) * 32 + cc] = v.z;
        sf[(row0 + 3) * 32 + cc] = v.w;
      }
    }
    __syncthreads();
#pragma unroll
    for (int it = 0; it < 16; ++it) {
      int lin = it * 256 + t;        // 4096 entries
      int bi = lin >> 5, c2 = lin & 31;
      size_t o = (size_t)(m0 + bi) * NC + c2;
      negout[o] = -sf[bi * 32 + c2];
      codefout[o] = (float)lcode[bi * 33 + c2];
    }
  }
}

// ---------------------------------------------------------------------------
extern "C" void kernel_launch(void* const* d_in, const int* in_sizes, int n_in,
                              void* d_out, int out_size, void* d_ws, size_t ws_size,
                              hipStream_t stream) {
  const float* inputs = (const float*)d_in[0];   // (B, C, 16) f32
  const float* cents  = (const float*)d_in[1];   // (C, K, 16) f32
  const float* W      = (const float*)d_in[2];   // (512, 512) f32

  float* out = (float*)d_out;
  float* negout   = out + (size_t)NB * NDOUT;            // (B, C)
  float* codefout = negout + (size_t)NB * NC;            // (B, C) as float

  unsigned short* Wt      = (unsigned short*)d_ws;                          // 512 KiB
  unsigned short* centsH  = (unsigned short*)((char*)d_ws + 512 * 1024);    // 256 KiB
  unsigned short* centsP4 = (unsigned short*)((char*)d_ws + (1 << 20));     // 512 KiB
  float* T_neg            = (float*)((char*)d_ws + 2 * (1 << 20));          // 4 MiB
  int* T_code             = (int*)((char*)d_ws + 6 * (1 << 20));            // 4 MiB

  k_prep<<<288, 256, 0, stream>>>(W, cents, Wt, centsH, centsP4);
  k_score<<<dim3(NB / 128, NC), 256, 0, stream>>>(inputs, centsP4, cents, T_neg, T_code);
  k_gemm<<<dim3(NB / 128, NDOUT / 128), 256, 0, stream>>>(centsH, T_code, T_neg, Wt, out,
                                                          negout, codefout);
}

// Round 16
// 102.526 us; speedup vs baseline: 1.0348x; 1.0348x over previous
//
#include <hip/hip_runtime.h>

// DPQ network:
//  k_score : response argmax via FULL-split bf16 MFMA ((ah+al)(bh+bl));
//            areg[16] one-burst hoist (no-spill, 4 waves/SIMD — HW occupancy
//            granularity makes >4 unreachable per m69); B-loads issued first;
//            setprio(1) around main loop; CERT=0.002 + inline exact rescue
//  k_finish: pure tile-transpose [c][b] -> [b][c]
//  k_gemm  : codebook-gather GEMM (bf16 MFMA), reads T_code directly
// B=32768, C=32, K=256, D_SUB=16, D_IN=512, D_OUT=512

#define NB 32768
#define NC 32
#define NK 256
#define NDS 16
#define NDIN 512
#define NDOUT 512
#define CERT 0.002f

typedef __attribute__((ext_vector_type(8))) short s8v;          // 8 bf16
typedef __attribute__((ext_vector_type(4))) float f4v;          // MFMA acc
typedef __attribute__((ext_vector_type(4))) unsigned int u4v;   // 4 u32 = 8 bf16

__device__ __forceinline__ unsigned short f2bf(float f) {
  unsigned int u = __float_as_uint(f);
  u += 0x7fffu + ((u >> 16) & 1u);   // RNE
  return (unsigned short)(u >> 16);
}
__device__ __forceinline__ float bf2f(unsigned short h) {
  return __uint_as_float(((unsigned int)h) << 16);
}

// packed f32->bf16 (RNE), 2 values per instruction
#define CVTPK(d, lo, hi) \
  asm("v_cvt_pk_bf16_f32 %0, %1, %2" : "=v"(d) : "v"(lo), "v"(hi))

__device__ __forceinline__ void gload16(const void* g, void* l) {
  __builtin_amdgcn_global_load_lds(
      (const __attribute__((address_space(1))) void*)g,
      (__attribute__((address_space(3))) void*)l, 16, 0, 0);
}

// exact f32 dot over 16 dims, sequential fold (same association everywhere)
__device__ __forceinline__ float dot16(const float* x, const float* cj) {
  float4 a0 = *(const float4*)(x + 0),  a1 = *(const float4*)(x + 4);
  float4 a2 = *(const float4*)(x + 8),  a3 = *(const float4*)(x + 12);
  float4 c0 = *(const float4*)(cj + 0), c1 = *(const float4*)(cj + 4);
  float4 c2 = *(const float4*)(cj + 8), c3 = *(const float4*)(cj + 12);
  float s = a0.x * c0.x;
  s = fmaf(a0.y, c0.y, s); s = fmaf(a0.z, c0.z, s); s = fmaf(a0.w, c0.w, s);
  s = fmaf(a1.x, c1.x, s); s = fmaf(a1.y, c1.y, s); s = fmaf(a1.z, c1.z, s); s = fmaf(a1.w, c1.w, s);
  s = fmaf(a2.x, c2.x, s); s = fmaf(a2.y, c2.y, s); s = fmaf(a2.z, c2.z, s); s = fmaf(a2.w, c2.w, s);
  s = fmaf(a3.x, c3.x, s); s = fmaf(a3.y, c3.y, s); s = fmaf(a3.z, c3.z, s); s = fmaf(a3.w, c3.w, s);
  return s;
}

// ---------------------------------------------------------------------------
// Kernel 0: Wt[n][k] = bf16(W[k][n]); centsH = flat bf16 (gemm gather source);
//           centsP4[c][plane][k][8]: plane 0 hi d0-7, 1 hi d8-15, 2 lo d0-7,
//           3 lo d8-15 (A-fragment order)
// ---------------------------------------------------------------------------
__global__ __launch_bounds__(256) void k_prep(const float* __restrict__ W,
                                              const float* __restrict__ cents,
                                              unsigned short* __restrict__ Wt,
                                              unsigned short* __restrict__ centsH,
                                              unsigned short* __restrict__ centsP4) {
  const int t = threadIdx.x;
  const int bid = blockIdx.x;
  if (bid < 256) {
    __shared__ float tile[32][33];
    const int k0 = (bid >> 4) << 5;
    const int n0 = (bid & 15) << 5;
    const int tx = t & 31, ty = t >> 5;
#pragma unroll
    for (int i = 0; i < 4; ++i) {
      int r = ty + i * 8;
      tile[r][tx] = W[(size_t)(k0 + r) * NDOUT + n0 + tx];
    }
    __syncthreads();
#pragma unroll
    for (int i = 0; i < 4; ++i) {
      int r = ty + i * 8;
      Wt[(size_t)(n0 + r) * NDIN + k0 + tx] = f2bf(tile[tx][r]);
    }
  } else {
    // per-c codebook processing: c = bid-256, thread t = k
    const int c = bid - 256;
    const int k = t;
    const float* src = cents + ((size_t)c * NK + k) * NDS;
    unsigned short hi[16], lo[16];
#pragma unroll
    for (int j = 0; j < 4; ++j) {
      float4 v = *(const float4*)(src + j * 4);
      unsigned short h0 = f2bf(v.x), h1 = f2bf(v.y), h2 = f2bf(v.z), h3 = f2bf(v.w);
      hi[j * 4 + 0] = h0; hi[j * 4 + 1] = h1; hi[j * 4 + 2] = h2; hi[j * 4 + 3] = h3;
      lo[j * 4 + 0] = f2bf(v.x - bf2f(h0));
      lo[j * 4 + 1] = f2bf(v.y - bf2f(h1));
      lo[j * 4 + 2] = f2bf(v.z - bf2f(h2));
      lo[j * 4 + 3] = f2bf(v.w - bf2f(h3));
    }
    unsigned short* hf = centsH + ((size_t)c * NK + k) * NDS;
#pragma unroll
    for (int j = 0; j < 4; ++j)
      *(ushort4*)(hf + j * 4) = make_ushort4(hi[j * 4], hi[j * 4 + 1], hi[j * 4 + 2], hi[j * 4 + 3]);
    unsigned short* pb = centsP4 + (size_t)c * 8192 + k * 8;
    *(ushort4*)(pb + 0 * 2048 + 0) = make_ushort4(hi[0], hi[1], hi[2], hi[3]);
    *(ushort4*)(pb + 0 * 2048 + 4) = make_ushort4(hi[4], hi[5], hi[6], hi[7]);
    *(ushort4*)(pb + 1 * 2048 + 0) = make_ushort4(hi[8], hi[9], hi[10], hi[11]);
    *(ushort4*)(pb + 1 * 2048 + 4) = make_ushort4(hi[12], hi[13], hi[14], hi[15]);
    *(ushort4*)(pb + 2 * 2048 + 0) = make_ushort4(lo[0], lo[1], lo[2], lo[3]);
    *(ushort4*)(pb + 2 * 2048 + 4) = make_ushort4(lo[4], lo[5], lo[6], lo[7]);
    *(ushort4*)(pb + 3 * 2048 + 0) = make_ushort4(lo[8], lo[9], lo[10], lo[11]);
    *(ushort4*)(pb + 3 * 2048 + 4) = make_ushort4(lo[12], lo[13], lo[14], lo[15]);
  }
}

// build hi-packed s8v + residuals from 8 f32 (u0,u1)
__device__ __forceinline__ void split8(float4 u0, float4 u1, s8v& bh, s8v& bl) {
  unsigned int ph0, ph1, ph2, ph3;
  CVTPK(ph0, u0.x, u0.y); CVTPK(ph1, u0.z, u0.w);
  CVTPK(ph2, u1.x, u1.y); CVTPK(ph3, u1.z, u1.w);
  bh = __builtin_bit_cast(s8v, (u4v){ph0, ph1, ph2, ph3});
  float ra = u0.x - __uint_as_float(ph0 << 16);
  float rb = u0.y - __uint_as_float(ph0 & 0xFFFF0000u);
  float rc = u0.z - __uint_as_float(ph1 << 16);
  float rd = u0.w - __uint_as_float(ph1 & 0xFFFF0000u);
  float re = u1.x - __uint_as_float(ph2 << 16);
  float rf = u1.y - __uint_as_float(ph2 & 0xFFFF0000u);
  float rg = u1.z - __uint_as_float(ph3 << 16);
  float rh = u1.w - __uint_as_float(ph3 & 0xFFFF0000u);
  unsigned int pl0, pl1, pl2, pl3;
  CVTPK(pl0, ra, rb); CVTPK(pl1, rc, rd);
  CVTPK(pl2, re, rf); CVTPK(pl3, rg, rh);
  bl = __builtin_bit_cast(s8v, (u4v){pl0, pl1, pl2, pl3});
}

// track a pair of adjacent-k scores (kc0, kc0+1): ~8 VALU ops / 2 scores.
#define TRACK2(v0, v1, kc0, best, sec, bk)                     \
  {                                                            \
    float vm_ = fmaxf(v0, v1);                                 \
    float md_ = __builtin_amdgcn_fmed3f(best, v0, v1);         \
    sec = fmaxf(sec, md_);                                     \
    int km_ = (v1 > v0) ? (kc0 + 1) : (kc0);                   \
    bool gt_ = vm_ > best;                                     \
    bk = gt_ ? km_ : bk;                                       \
    best = fmaxf(best, vm_);                                   \
  }

// ---------------------------------------------------------------------------
// k_score: per wave = 32 b's x 1 c. B-row loads issued FIRST (overlap with
// A-burst); areg[16] hoist; FULL-split pairing: A = [ah|al] by lane,
// pass1 B = [bh|bl], pass2 B = [bl|bh] => acc = (ah+al)(bh+bl).
// setprio(1) wraps the MFMA+track loop (independent-wave regime, T5/m191).
// Tracking/butterfly/finalize/rescue verbatim from passing R14.
// ---------------------------------------------------------------------------
__global__ __launch_bounds__(256, 4) void k_score(const float* __restrict__ inputs,
                                                  const unsigned short* __restrict__ centsP4,
                                                  const float* __restrict__ cents,
                                                  float* __restrict__ T_neg,
                                                  int* __restrict__ T_code) {
  const int t = threadIdx.x;
  const int l = t & 63;
  const int w = t >> 6;
  const int c = blockIdx.y;
  const int b0 = blockIdx.x * 128 + w * 32;   // this wave: b0..b0+31 (two 16-col subtiles)
  const int g = l >> 4;
  const int col = l & 15;
  const int dh = (g & 1) * 8;
  const int g4 = g * 4;

  // ---- issue B-row loads first (their latency overlaps the A-burst issue)
  const float* r0 = inputs + ((size_t)(b0 + col) * NC + c) * NDS + dh;
  const float* r1 = inputs + ((size_t)(b0 + 16 + col) * NC + c) * NDS + dh;
  float4 u0 = *(const float4*)(r0), u1 = *(const float4*)(r0 + 4);
  float4 v0 = *(const float4*)(r1), v1 = *(const float4*)(r1 + 4);

  // ---- hoist all 16 A-fragments into registers (independent 16B loads)
  const unsigned short* abase = centsP4 + (size_t)c * 8192 + g * 2048 + col * 8;
  s8v areg[16];
#pragma unroll
  for (int kt = 0; kt < 16; ++kt)
    areg[kt] = *(const s8v*)(abase + kt * 128);

  // ---- B fragments (two subtiles), hi/lo split via cvt_pk; full-split pairing
  s8v p1f0, p2f0, p1f1, p2f1;
  {
    s8v bh0, bl0, bh1, bl1;
    split8(u0, u1, bh0, bl0);
    split8(v0, v1, bh1, bl1);
    const bool hiLane = (l < 32);             // kappa 0-15 lanes
    p1f0 = hiLane ? bh0 : bl0;                // pass1: [bh | bl]
    p2f0 = hiLane ? bl0 : bh0;                // pass2: [bl | bh]
    p1f1 = hiLane ? bh1 : bl1;
    p2f1 = hiLane ? bl1 : bh1;
  }

  float best0 = -3.0e38f, sec0 = -3.0e38f;
  float best1 = -3.0e38f, sec1 = -3.0e38f;
  int bk0 = 0, bk1 = 0;
  const f4v zz = {0.0f, 0.0f, 0.0f, 0.0f};

  __builtin_amdgcn_s_setprio(1);
#pragma unroll
  for (int kt = 0; kt < 16; ++kt) {
    s8v a = areg[kt];                          // register-resident
    f4v acc0 = __builtin_amdgcn_mfma_f32_16x16x32_bf16(a, p1f0, zz, 0, 0, 0);
    acc0 = __builtin_amdgcn_mfma_f32_16x16x32_bf16(a, p2f0, acc0, 0, 0, 0);
    f4v acc1 = __builtin_amdgcn_mfma_f32_16x16x32_bf16(a, p1f1, zz, 0, 0, 0);
    acc1 = __builtin_amdgcn_mfma_f32_16x16x32_bf16(a, p2f1, acc1, 0, 0, 0);
    const int kc = kt * 16;
    TRACK2(acc0[0], acc0[1], kc + 0, best0, sec0, bk0)
    TRACK2(acc0[2], acc0[3], kc + 2, best0, sec0, bk0)
    TRACK2(acc1[0], acc1[1], kc + 0, best1, sec1, bk1)
    TRACK2(acc1[2], acc1[3], kc + 2, best1, sec1, bk1)
  }
  __builtin_amdgcn_s_setprio(0);

  bk0 += g4;
  bk1 += g4;

  // butterfly across the 4 lane-groups (verbatim)
#pragma unroll
  for (int off = 16; off <= 32; off <<= 1) {
    float vb = __shfl_xor(best0, off);
    float sb = __shfl_xor(sec0, off);
    int kb = __shfl_xor(bk0, off);
    float mn = fminf(best0, vb);
    sec0 = fmaxf(fmaxf(sec0, sb), mn);
    bool take = (vb > best0) || (vb == best0 && kb < bk0);
    bk0 = take ? kb : bk0;
    best0 = fmaxf(best0, vb);

    vb = __shfl_xor(best1, off);
    sb = __shfl_xor(sec1, off);
    kb = __shfl_xor(bk1, off);
    mn = fminf(best1, vb);
    sec1 = fmaxf(fmaxf(sec1, sb), mn);
    take = (vb > best1) || (vb == best1 && kb < bk1);
    bk1 = take ? kb : bk1;
    best1 = fmaxf(best1, vb);
  }

  // per-result-lane final values (lanes 0..31 own b = b0 + l)
  const int sub = (l >> 4) & 1;
  float best = sub ? best1 : best0;
  float sec = sub ? sec1 : sec0;
  int bk = sub ? bk1 : bk0;
  const bool owner = (l < 32);
  const bool flagged = owner && (best - sec <= CERT);

  if (owner && !flagged) {
    const int b = b0 + l;
    const float* xr = inputs + ((size_t)b * NC + c) * NDS;
    const float* cr = cents + ((size_t)c * NK + bk) * NDS;
    size_t o = (size_t)c * NB + b;
    T_neg[o] = dot16(xr, cr);
    T_code[o] = bk;
  }

  // inline rescue: whole wave rescans flagged entries exactly (verbatim)
  unsigned long long mask = __ballot(flagged);
  while (mask) {
    const int p = __builtin_ctzll(mask);
    mask &= mask - 1;
    const int b = b0 + p;
    const float* xr = inputs + ((size_t)b * NC + c) * NDS;
    const float* cr = cents + ((size_t)c * NK + l * 4) * NDS;
    float rb = -3.0e38f;
    int rk = 0;
#pragma unroll
    for (int q = 0; q < 4; ++q) {
      float d = dot16(xr, cr + q * NDS);
      if (d > rb) { rb = d; rk = l * 4 + q; }   // strict >, ascending k
    }
#pragma unroll
    for (int off = 1; off <= 32; off <<= 1) {
      float vb = __shfl_xor(rb, off);
      int kb = __shfl_xor(rk, off);
      bool take = (vb > rb) || (vb == rb && kb < rk);
      rb = take ? vb : rb;
      rk = take ? kb : rk;
    }
    if (l == 0) {
      size_t o = (size_t)c * NB + b;
      T_neg[o] = rb;
      T_code[o] = rk;
    }
  }
}

// ---------------------------------------------------------------------------
// k_finish: pure transpose of negout/codefout
// ---------------------------------------------------------------------------
__global__ __launch_bounds__(256) void k_finish(const float* __restrict__ T_neg,
                                                const int* __restrict__ T_code,
                                                float* __restrict__ negout,
                                                float* __restrict__ codefout) {
  __shared__ float sneg[64][33];
  __shared__ int scode[64][33];
  const int t = threadIdx.x;
  const int b0 = blockIdx.x * 64;

#pragma unroll
  for (int it = 0; it < 8; ++it) {
    int lin = it * 256 + t;
    int c = lin >> 6, bi = lin & 63;
    sneg[bi][c] = T_neg[(size_t)c * NB + b0 + bi];
    scode[bi][c] = T_code[(size_t)c * NB + b0 + bi];
  }
  __syncthreads();

#pragma unroll
  for (int it = 0; it < 8; ++it) {
    int lin = it * 256 + t;
    int bi = lin >> 5, c = lin & 31;
    size_t o = (size_t)(b0 + bi) * NC + c;
    negout[o] = -sneg[bi][c];
    codefout[o] = (float)scode[bi][c];
  }
}

// ---------------------------------------------------------------------------
// Kernel 2: product = gather(centsH, codes) @ W  via bf16 MFMA.
// Codes read directly from T_code[c][b] (coalesced 512B segments per c).
// ---------------------------------------------------------------------------
__global__ __launch_bounds__(256) void k_gemm(const unsigned short* __restrict__ centsB,
                                              const int* __restrict__ T_code,
                                              const unsigned short* __restrict__ Wt,
                                              float* __restrict__ out) {
  __shared__ __align__(16) unsigned short As[128 * 64];
  __shared__ __align__(16) unsigned short Bs[128 * 64];
  __shared__ int lcode[128 * 33];

  const int t = threadIdx.x;
  const int l = t & 63;
  const int w = t >> 6;
  const int wm = w >> 1, wn = w & 1;
  const int m0 = blockIdx.x * 128;
  const int n0 = blockIdx.y * 128;

  {
    // lcode[row][col] = T_code[col*NB + m0 + row]
    const int cc = t >> 3;          // 0..31
    const int ch = t & 7;           // 0..7 -> rows ch*16..ch*16+15
#pragma unroll
    for (int i = 0; i < 4; ++i) {
      int row0 = ch * 16 + i * 4;
      int4 v = *(const int4*)(T_code + (size_t)cc * NB + m0 + row0);
      lcode[(row0 + 0) * 33 + cc] = v.x;
      lcode[(row0 + 1) * 33 + cc] = v.y;
      lcode[(row0 + 2) * 33 + cc] = v.z;
      lcode[(row0 + 3) * 33 + cc] = v.w;
    }
  }

  f4v acc[4][4] = {};
  const int s = t & 7;
  const int rq = t >> 3;

  for (int kt = 0; kt < 8; ++kt) {
    __syncthreads();
    const int c0 = kt * 4;
#pragma unroll
    for (int i = 0; i < 4; ++i) {
      int lr = i * 32 + rq;
      int srcslot = s ^ (lr & 7);
      int cl = srcslot >> 1, half = srcslot & 1;
      int code = lcode[lr * 33 + c0 + cl];
      const unsigned short* gsrc =
          centsB + ((size_t)((c0 + cl) * NK + code) * NDS + half * 8);
      gload16(gsrc, (char*)As + i * 4096 + (w << 10));
    }
#pragma unroll
    for (int i = 0; i < 4; ++i) {
      int lr = i * 32 + rq;
      int k16 = s ^ (lr & 7);
      const unsigned short* gsrc = Wt + (size_t)(n0 + lr) * NDIN + kt * 64 + k16 * 8;
      gload16(gsrc, (char*)Bs + i * 4096 + (w << 10));
    }
    __syncthreads();

    s8v af[4][2], bfr[4][2];
#pragma unroll
    for (int mf = 0; mf < 4; ++mf)
#pragma unroll
      for (int ks = 0; ks < 2; ++ks) {
        int row = wm * 64 + mf * 16 + (l & 15);
        int slot = ks * 4 + (l >> 4);
        af[mf][ks] = *(const s8v*)((const char*)As + row * 128 + ((slot ^ (row & 7)) << 4));
      }
#pragma unroll
    for (int nf = 0; nf < 4; ++nf)
#pragma unroll
      for (int ks = 0; ks < 2; ++ks) {
        int row = wn * 64 + nf * 16 + (l & 15);
        int slot = ks * 4 + (l >> 4);
        bfr[nf][ks] = *(const s8v*)((const char*)Bs + row * 128 + ((slot ^ (row & 7)) << 4));
      }
#pragma unroll
    for (int ks = 0; ks < 2; ++ks)
#pragma unroll
      for (int mf = 0; mf < 4; ++mf)
#pragma unroll
        for (int nf = 0; nf < 4; ++nf)
          acc[mf][nf] = __builtin_amdgcn_mfma_f32_16x16x32_bf16(
              af[mf][ks], bfr[nf][ks], acc[mf][nf], 0, 0, 0);
  }

#pragma unroll
  for (int mf = 0; mf < 4; ++mf)
#pragma unroll
    for (int nf = 0; nf < 4; ++nf)
#pragma unroll
      for (int r = 0; r < 4; ++r) {
        int row = m0 + wm * 64 + mf * 16 + (l >> 4) * 4 + r;
        int col = n0 + wn * 64 + nf * 16 + (l & 15);
        out[(size_t)row * NDOUT + col] = acc[mf][nf][r];
      }
}

// ---------------------------------------------------------------------------
extern "C" void kernel_launch(void* const* d_in, const int* in_sizes, int n_in,
                              void* d_out, int out_size, void* d_ws, size_t ws_size,
                              hipStream_t stream) {
  const float* inputs = (const float*)d_in[0];   // (B, C, 16) f32
  const float* cents  = (const float*)d_in[1];   // (C, K, 16) f32
  const float* W      = (const float*)d_in[2];   // (512, 512) f32

  float* out = (float*)d_out;
  float* negout   = out + (size_t)NB * NDOUT;            // (B, C)
  float* codefout = negout + (size_t)NB * NC;            // (B, C) as float

  unsigned short* Wt      = (unsigned short*)d_ws;                          // 512 KiB
  unsigned short* centsH  = (unsigned short*)((char*)d_ws + 512 * 1024);    // 256 KiB
  unsigned short* centsP4 = (unsigned short*)((char*)d_ws + (1 << 20));     // 512 KiB
  float* T_neg            = (float*)((char*)d_ws + 2 * (1 << 20));          // 4 MiB
  int* T_code             = (int*)((char*)d_ws + 6 * (1 << 20));            // 4 MiB

  k_prep<<<288, 256, 0, stream>>>(W, cents, Wt, centsH, centsP4);
  k_score<<<dim3(NB / 128, NC), 256, 0, stream>>>(inputs, centsP4, cents, T_neg, T_code);
  k_finish<<<NB / 64, 256, 0, stream>>>(T_neg, T_code, negout, codefout);
  k_gemm<<<dim3(NB / 128, NDOUT / 128), 256, 0, stream>>>(centsH, T_code, Wt, out);
}

// Round 17
// 100.123 us; speedup vs baseline: 1.0597x; 1.0240x over previous
//
#include <hip/hip_runtime.h>

// DPQ network:
//  k_score : response argmax via FULL-split bf16 MFMA ((ah+al)(bh+bl));
//            64 b's per wave (4 subtile chains A-D, per-wave overhead
//            amortized 2x, all 64 lanes finalize); areg[8]+prefetch reload;
//            cvt_pk B-prep; med3 pair tracking; setprio(1); CERT=0.002
//  k_finish: pure tile-transpose [c][b] -> [b][c]
//  k_gemm  : codebook-gather GEMM (bf16 MFMA), reads T_code directly
// B=32768, C=32, K=256, D_SUB=16, D_IN=512, D_OUT=512

#define NB 32768
#define NC 32
#define NK 256
#define NDS 16
#define NDIN 512
#define NDOUT 512
#define CERT 0.002f

typedef __attribute__((ext_vector_type(8))) short s8v;          // 8 bf16
typedef __attribute__((ext_vector_type(4))) float f4v;          // MFMA acc
typedef __attribute__((ext_vector_type(4))) unsigned int u4v;   // 4 u32 = 8 bf16

__device__ __forceinline__ unsigned short f2bf(float f) {
  unsigned int u = __float_as_uint(f);
  u += 0x7fffu + ((u >> 16) & 1u);   // RNE
  return (unsigned short)(u >> 16);
}
__device__ __forceinline__ float bf2f(unsigned short h) {
  return __uint_as_float(((unsigned int)h) << 16);
}

// packed f32->bf16 (RNE), 2 values per instruction
#define CVTPK(d, lo, hi) \
  asm("v_cvt_pk_bf16_f32 %0, %1, %2" : "=v"(d) : "v"(lo), "v"(hi))

__device__ __forceinline__ void gload16(const void* g, void* l) {
  __builtin_amdgcn_global_load_lds(
      (const __attribute__((address_space(1))) void*)g,
      (__attribute__((address_space(3))) void*)l, 16, 0, 0);
}

// exact f32 dot over 16 dims, sequential fold (same association everywhere)
__device__ __forceinline__ float dot16(const float* x, const float* cj) {
  float4 a0 = *(const float4*)(x + 0),  a1 = *(const float4*)(x + 4);
  float4 a2 = *(const float4*)(x + 8),  a3 = *(const float4*)(x + 12);
  float4 c0 = *(const float4*)(cj + 0), c1 = *(const float4*)(cj + 4);
  float4 c2 = *(const float4*)(cj + 8), c3 = *(const float4*)(cj + 12);
  float s = a0.x * c0.x;
  s = fmaf(a0.y, c0.y, s); s = fmaf(a0.z, c0.z, s); s = fmaf(a0.w, c0.w, s);
  s = fmaf(a1.x, c1.x, s); s = fmaf(a1.y, c1.y, s); s = fmaf(a1.z, c1.z, s); s = fmaf(a1.w, c1.w, s);
  s = fmaf(a2.x, c2.x, s); s = fmaf(a2.y, c2.y, s); s = fmaf(a2.z, c2.z, s); s = fmaf(a2.w, c2.w, s);
  s = fmaf(a3.x, c3.x, s); s = fmaf(a3.y, c3.y, s); s = fmaf(a3.z, c3.z, s); s = fmaf(a3.w, c3.w, s);
  return s;
}

// ---------------------------------------------------------------------------
// Kernel 0: Wt[n][k] = bf16(W[k][n]); centsH = flat bf16 (gemm gather source);
//           centsP4[c][plane][k][8]: plane 0 hi d0-7, 1 hi d8-15, 2 lo d0-7,
//           3 lo d8-15 (A-fragment order)
// ---------------------------------------------------------------------------
__global__ __launch_bounds__(256) void k_prep(const float* __restrict__ W,
                                              const float* __restrict__ cents,
                                              unsigned short* __restrict__ Wt,
                                              unsigned short* __restrict__ centsH,
                                              unsigned short* __restrict__ centsP4) {
  const int t = threadIdx.x;
  const int bid = blockIdx.x;
  if (bid < 256) {
    __shared__ float tile[32][33];
    const int k0 = (bid >> 4) << 5;
    const int n0 = (bid & 15) << 5;
    const int tx = t & 31, ty = t >> 5;
#pragma unroll
    for (int i = 0; i < 4; ++i) {
      int r = ty + i * 8;
      tile[r][tx] = W[(size_t)(k0 + r) * NDOUT + n0 + tx];
    }
    __syncthreads();
#pragma unroll
    for (int i = 0; i < 4; ++i) {
      int r = ty + i * 8;
      Wt[(size_t)(n0 + r) * NDIN + k0 + tx] = f2bf(tile[tx][r]);
    }
  } else {
    // per-c codebook processing: c = bid-256, thread t = k
    const int c = bid - 256;
    const int k = t;
    const float* src = cents + ((size_t)c * NK + k) * NDS;
    unsigned short hi[16], lo[16];
#pragma unroll
    for (int j = 0; j < 4; ++j) {
      float4 v = *(const float4*)(src + j * 4);
      unsigned short h0 = f2bf(v.x), h1 = f2bf(v.y), h2 = f2bf(v.z), h3 = f2bf(v.w);
      hi[j * 4 + 0] = h0; hi[j * 4 + 1] = h1; hi[j * 4 + 2] = h2; hi[j * 4 + 3] = h3;
      lo[j * 4 + 0] = f2bf(v.x - bf2f(h0));
      lo[j * 4 + 1] = f2bf(v.y - bf2f(h1));
      lo[j * 4 + 2] = f2bf(v.z - bf2f(h2));
      lo[j * 4 + 3] = f2bf(v.w - bf2f(h3));
    }
    unsigned short* hf = centsH + ((size_t)c * NK + k) * NDS;
#pragma unroll
    for (int j = 0; j < 4; ++j)
      *(ushort4*)(hf + j * 4) = make_ushort4(hi[j * 4], hi[j * 4 + 1], hi[j * 4 + 2], hi[j * 4 + 3]);
    unsigned short* pb = centsP4 + (size_t)c * 8192 + k * 8;
    *(ushort4*)(pb + 0 * 2048 + 0) = make_ushort4(hi[0], hi[1], hi[2], hi[3]);
    *(ushort4*)(pb + 0 * 2048 + 4) = make_ushort4(hi[4], hi[5], hi[6], hi[7]);
    *(ushort4*)(pb + 1 * 2048 + 0) = make_ushort4(hi[8], hi[9], hi[10], hi[11]);
    *(ushort4*)(pb + 1 * 2048 + 4) = make_ushort4(hi[12], hi[13], hi[14], hi[15]);
    *(ushort4*)(pb + 2 * 2048 + 0) = make_ushort4(lo[0], lo[1], lo[2], lo[3]);
    *(ushort4*)(pb + 2 * 2048 + 4) = make_ushort4(lo[4], lo[5], lo[6], lo[7]);
    *(ushort4*)(pb + 3 * 2048 + 0) = make_ushort4(lo[8], lo[9], lo[10], lo[11]);
    *(ushort4*)(pb + 3 * 2048 + 4) = make_ushort4(lo[12], lo[13], lo[14], lo[15]);
  }
}

// build hi-packed s8v + residuals from 8 f32 (u0,u1)
__device__ __forceinline__ void split8(float4 u0, float4 u1, s8v& bh, s8v& bl) {
  unsigned int ph0, ph1, ph2, ph3;
  CVTPK(ph0, u0.x, u0.y); CVTPK(ph1, u0.z, u0.w);
  CVTPK(ph2, u1.x, u1.y); CVTPK(ph3, u1.z, u1.w);
  bh = __builtin_bit_cast(s8v, (u4v){ph0, ph1, ph2, ph3});
  float ra = u0.x - __uint_as_float(ph0 << 16);
  float rb = u0.y - __uint_as_float(ph0 & 0xFFFF0000u);
  float rc = u0.z - __uint_as_float(ph1 << 16);
  float rd = u0.w - __uint_as_float(ph1 & 0xFFFF0000u);
  float re = u1.x - __uint_as_float(ph2 << 16);
  float rf = u1.y - __uint_as_float(ph2 & 0xFFFF0000u);
  float rg = u1.z - __uint_as_float(ph3 << 16);
  float rh = u1.w - __uint_as_float(ph3 & 0xFFFF0000u);
  unsigned int pl0, pl1, pl2, pl3;
  CVTPK(pl0, ra, rb); CVTPK(pl1, rc, rd);
  CVTPK(pl2, re, rf); CVTPK(pl3, rg, rh);
  bl = __builtin_bit_cast(s8v, (u4v){pl0, pl1, pl2, pl3});
}

// track a pair of adjacent-k scores (kc0, kc0+1): ~8 VALU ops / 2 scores.
#define TRACK2(v0, v1, kc0, best, sec, bk)                     \
  {                                                            \
    float vm_ = fmaxf(v0, v1);                                 \
    float md_ = __builtin_amdgcn_fmed3f(best, v0, v1);         \
    sec = fmaxf(sec, md_);                                     \
    int km_ = (v1 > v0) ? (kc0 + 1) : (kc0);                   \
    bool gt_ = vm_ > best;                                     \
    bk = gt_ ? km_ : bk;                                       \
    best = fmaxf(best, vm_);                                   \
  }

// MFMA pair + tracking for one chain at one kt
#define CHAIN_STEP(a, p1, p2, kc, best, sec, bk)                             \
  {                                                                          \
    f4v acc_ = __builtin_amdgcn_mfma_f32_16x16x32_bf16(a, p1, zz, 0, 0, 0);  \
    acc_ = __builtin_amdgcn_mfma_f32_16x16x32_bf16(a, p2, acc_, 0, 0, 0);    \
    TRACK2(acc_[0], acc_[1], kc + 0, best, sec, bk)                          \
    TRACK2(acc_[2], acc_[3], kc + 2, best, sec, bk)                          \
  }

// butterfly-combine one chain across the 4 lane-groups
#define BFLY(best, sec, bk)                                    \
  {                                                            \
    _Pragma("unroll")                                          \
    for (int off = 16; off <= 32; off <<= 1) {                 \
      float vb = __shfl_xor(best, off);                        \
      float sb = __shfl_xor(sec, off);                         \
      int kb = __shfl_xor(bk, off);                            \
      float mn = fminf(best, vb);                              \
      sec = fmaxf(fmaxf(sec, sb), mn);                         \
      bool take = (vb > best) || (vb == best && kb < bk);      \
      bk = take ? kb : bk;                                     \
      best = fmaxf(best, vb);                                  \
    }                                                          \
  }

// ---------------------------------------------------------------------------
// k_score: per wave = 64 b's x 1 c (4 subtile chains). B-loads issued first;
// areg[8] + prefetch reload; FULL-split pairing per chain; setprio(1) around
// main loop. Lane l finalizes b = b0 + l (all 64 lanes owners).
// ---------------------------------------------------------------------------
__global__ __launch_bounds__(256, 4) void k_score(const float* __restrict__ inputs,
                                                  const unsigned short* __restrict__ centsP4,
                                                  const float* __restrict__ cents,
                                                  float* __restrict__ T_neg,
                                                  int* __restrict__ T_code) {
  const int t = threadIdx.x;
  const int l = t & 63;
  const int w = t >> 6;
  const int c = blockIdx.y;
  const int b0 = blockIdx.x * 256 + w * 64;   // this wave: b0..b0+63 (4 subtiles)
  const int g = l >> 4;
  const int col = l & 15;
  const int dh = (g & 1) * 8;
  const int g4 = g * 4;

  // ---- issue B-row loads first (latency overlaps the A-burst issue)
  const float* r0 = inputs + ((size_t)(b0 + col) * NC + c) * NDS + dh;
  const float* r1 = inputs + ((size_t)(b0 + 16 + col) * NC + c) * NDS + dh;
  const float* r2 = inputs + ((size_t)(b0 + 32 + col) * NC + c) * NDS + dh;
  const float* r3 = inputs + ((size_t)(b0 + 48 + col) * NC + c) * NDS + dh;
  float4 uA0 = *(const float4*)(r0), uA1 = *(const float4*)(r0 + 4);
  float4 uB0 = *(const float4*)(r1), uB1 = *(const float4*)(r1 + 4);
  float4 uC0 = *(const float4*)(r2), uC1 = *(const float4*)(r2 + 4);
  float4 uD0 = *(const float4*)(r3), uD1 = *(const float4*)(r3 + 4);

  // ---- first 8 A-fragments (independent 16B loads)
  const unsigned short* abase = centsP4 + (size_t)c * 8192 + g * 2048 + col * 8;
  s8v areg[8];
#pragma unroll
  for (int kt = 0; kt < 8; ++kt)
    areg[kt] = *(const s8v*)(abase + kt * 128);

  // ---- B fragments (4 subtiles), hi/lo split via cvt_pk; full-split pairing
  s8v p1A, p2A, p1B, p2B, p1C, p2C, p1D, p2D;
  {
    s8v bh, bl;
    const bool hiLane = (l < 32);             // kappa 0-15 lanes
    split8(uA0, uA1, bh, bl); p1A = hiLane ? bh : bl; p2A = hiLane ? bl : bh;
    split8(uB0, uB1, bh, bl); p1B = hiLane ? bh : bl; p2B = hiLane ? bl : bh;
    split8(uC0, uC1, bh, bl); p1C = hiLane ? bh : bl; p2C = hiLane ? bl : bh;
    split8(uD0, uD1, bh, bl); p1D = hiLane ? bh : bl; p2D = hiLane ? bl : bh;
  }

  float bestA = -3.0e38f, secA = -3.0e38f;
  float bestB = -3.0e38f, secB = -3.0e38f;
  float bestC = -3.0e38f, secC = -3.0e38f;
  float bestD = -3.0e38f, secD = -3.0e38f;
  int bkA = 0, bkB = 0, bkC = 0, bkD = 0;
  const f4v zz = {0.0f, 0.0f, 0.0f, 0.0f};

  __builtin_amdgcn_s_setprio(1);
#pragma unroll
  for (int kt = 0; kt < 8; ++kt) {
    s8v a = areg[kt];
    areg[kt] = *(const s8v*)(abase + (kt + 8) * 128);   // prefetch kt+8
    const int kc = kt * 16;
    CHAIN_STEP(a, p1A, p2A, kc, bestA, secA, bkA)
    CHAIN_STEP(a, p1B, p2B, kc, bestB, secB, bkB)
    CHAIN_STEP(a, p1C, p2C, kc, bestC, secC, bkC)
    CHAIN_STEP(a, p1D, p2D, kc, bestD, secD, bkD)
  }
#pragma unroll
  for (int kt = 8; kt < 16; ++kt) {
    s8v a = areg[kt - 8];
    const int kc = kt * 16;
    CHAIN_STEP(a, p1A, p2A, kc, bestA, secA, bkA)
    CHAIN_STEP(a, p1B, p2B, kc, bestB, secB, bkB)
    CHAIN_STEP(a, p1C, p2C, kc, bestC, secC, bkC)
    CHAIN_STEP(a, p1D, p2D, kc, bestD, secD, bkD)
  }
  __builtin_amdgcn_s_setprio(0);

  bkA += g4; bkB += g4; bkC += g4; bkD += g4;

  BFLY(bestA, secA, bkA)
  BFLY(bestB, secB, bkB)
  BFLY(bestC, secC, bkC)
  BFLY(bestD, secD, bkD)

  // finalize: lane l owns b = b0 + l (chain = l>>4)
  float best = (g == 0) ? bestA : (g == 1) ? bestB : (g == 2) ? bestC : bestD;
  float sec  = (g == 0) ? secA  : (g == 1) ? secB  : (g == 2) ? secC  : secD;
  int bk     = (g == 0) ? bkA   : (g == 1) ? bkB   : (g == 2) ? bkC   : bkD;
  const bool flagged = (best - sec <= CERT);

  if (!flagged) {
    const int b = b0 + l;
    const float* xr = inputs + ((size_t)b * NC + c) * NDS;
    const float* cr = cents + ((size_t)c * NK + bk) * NDS;
    size_t o = (size_t)c * NB + b;
    T_neg[o] = dot16(xr, cr);
    T_code[o] = bk;
  }

  // inline rescue: whole wave rescans flagged entries exactly
  unsigned long long mask = __ballot(flagged);
  while (mask) {
    const int p = __builtin_ctzll(mask);
    mask &= mask - 1;
    const int b = b0 + p;
    const float* xr = inputs + ((size_t)b * NC + c) * NDS;
    const float* cr = cents + ((size_t)c * NK + l * 4) * NDS;
    float rb = -3.0e38f;
    int rk = 0;
#pragma unroll
    for (int q = 0; q < 4; ++q) {
      float d = dot16(xr, cr + q * NDS);
      if (d > rb) { rb = d; rk = l * 4 + q; }   // strict >, ascending k
    }
#pragma unroll
    for (int off = 1; off <= 32; off <<= 1) {
      float vb = __shfl_xor(rb, off);
      int kb = __shfl_xor(rk, off);
      bool take = (vb > rb) || (vb == rb && kb < rk);
      rb = take ? vb : rb;
      rk = take ? kb : rk;
    }
    if (l == 0) {
      size_t o = (size_t)c * NB + b;
      T_neg[o] = rb;
      T_code[o] = rk;
    }
  }
}

// ---------------------------------------------------------------------------
// k_finish: pure transpose of negout/codefout
// ---------------------------------------------------------------------------
__global__ __launch_bounds__(256) void k_finish(const float* __restrict__ T_neg,
                                                const int* __restrict__ T_code,
                                                float* __restrict__ negout,
                                                float* __restrict__ codefout) {
  __shared__ float sneg[64][33];
  __shared__ int scode[64][33];
  const int t = threadIdx.x;
  const int b0 = blockIdx.x * 64;

#pragma unroll
  for (int it = 0; it < 8; ++it) {
    int lin = it * 256 + t;
    int c = lin >> 6, bi = lin & 63;
    sneg[bi][c] = T_neg[(size_t)c * NB + b0 + bi];
    scode[bi][c] = T_code[(size_t)c * NB + b0 + bi];
  }
  __syncthreads();

#pragma unroll
  for (int it = 0; it < 8; ++it) {
    int lin = it * 256 + t;
    int bi = lin >> 5, c = lin & 31;
    size_t o = (size_t)(b0 + bi) * NC + c;
    negout[o] = -sneg[bi][c];
    codefout[o] = (float)scode[bi][c];
  }
}

// ---------------------------------------------------------------------------
// Kernel 2: product = gather(centsH, codes) @ W  via bf16 MFMA.
// Codes read directly from T_code[c][b] (coalesced 512B segments per c).
// ---------------------------------------------------------------------------
__global__ __launch_bounds__(256) void k_gemm(const unsigned short* __restrict__ centsB,
                                              const int* __restrict__ T_code,
                                              const unsigned short* __restrict__ Wt,
                                              float* __restrict__ out) {
  __shared__ __align__(16) unsigned short As[128 * 64];
  __shared__ __align__(16) unsigned short Bs[128 * 64];
  __shared__ int lcode[128 * 33];

  const int t = threadIdx.x;
  const int l = t & 63;
  const int w = t >> 6;
  const int wm = w >> 1, wn = w & 1;
  const int m0 = blockIdx.x * 128;
  const int n0 = blockIdx.y * 128;

  {
    // lcode[row][col] = T_code[col*NB + m0 + row]
    const int cc = t >> 3;          // 0..31
    const int ch = t & 7;           // 0..7 -> rows ch*16..ch*16+15
#pragma unroll
    for (int i = 0; i < 4; ++i) {
      int row0 = ch * 16 + i * 4;
      int4 v = *(const int4*)(T_code + (size_t)cc * NB + m0 + row0);
      lcode[(row0 + 0) * 33 + cc] = v.x;
      lcode[(row0 + 1) * 33 + cc] = v.y;
      lcode[(row0 + 2) * 33 + cc] = v.z;
      lcode[(row0 + 3) * 33 + cc] = v.w;
    }
  }

  f4v acc[4][4] = {};
  const int s = t & 7;
  const int rq = t >> 3;

  for (int kt = 0; kt < 8; ++kt) {
    __syncthreads();
    const int c0 = kt * 4;
#pragma unroll
    for (int i = 0; i < 4; ++i) {
      int lr = i * 32 + rq;
      int srcslot = s ^ (lr & 7);
      int cl = srcslot >> 1, half = srcslot & 1;
      int code = lcode[lr * 33 + c0 + cl];
      const unsigned short* gsrc =
          centsB + ((size_t)((c0 + cl) * NK + code) * NDS + half * 8);
      gload16(gsrc, (char*)As + i * 4096 + (w << 10));
    }
#pragma unroll
    for (int i = 0; i < 4; ++i) {
      int lr = i * 32 + rq;
      int k16 = s ^ (lr & 7);
      const unsigned short* gsrc = Wt + (size_t)(n0 + lr) * NDIN + kt * 64 + k16 * 8;
      gload16(gsrc, (char*)Bs + i * 4096 + (w << 10));
    }
    __syncthreads();

    s8v af[4][2], bfr[4][2];
#pragma unroll
    for (int mf = 0; mf < 4; ++mf)
#pragma unroll
      for (int ks = 0; ks < 2; ++ks) {
        int row = wm * 64 + mf * 16 + (l & 15);
        int slot = ks * 4 + (l >> 4);
        af[mf][ks] = *(const s8v*)((const char*)As + row * 128 + ((slot ^ (row & 7)) << 4));
      }
#pragma unroll
    for (int nf = 0; nf < 4; ++nf)
#pragma unroll
      for (int ks = 0; ks < 2; ++ks) {
        int row = wn * 64 + nf * 16 + (l & 15);
        int slot = ks * 4 + (l >> 4);
        bfr[nf][ks] = *(const s8v*)((const char*)Bs + row * 128 + ((slot ^ (row & 7)) << 4));
      }
#pragma unroll
    for (int ks = 0; ks < 2; ++ks)
#pragma unroll
      for (int mf = 0; mf < 4; ++mf)
#pragma unroll
        for (int nf = 0; nf < 4; ++nf)
          acc[mf][nf] = __builtin_amdgcn_mfma_f32_16x16x32_bf16(
              af[mf][ks], bfr[nf][ks], acc[mf][nf], 0, 0, 0);
  }

#pragma unroll
  for (int mf = 0; mf < 4; ++mf)
#pragma unroll
    for (int nf = 0; nf < 4; ++nf)
#pragma unroll
      for (int r = 0; r < 4; ++r) {
        int row = m0 + wm * 64 + mf * 16 + (l >> 4) * 4 + r;
        int col = n0 + wn * 64 + nf * 16 + (l & 15);
        out[(size_t)row * NDOUT + col] = acc[mf][nf][r];
      }
}

// ---------------------------------------------------------------------------
extern "C" void kernel_launch(void* const* d_in, const int* in_sizes, int n_in,
                              void* d_out, int out_size, void* d_ws, size_t ws_size,
                              hipStream_t stream) {
  const float* inputs = (const float*)d_in[0];   // (B, C, 16) f32
  const float* cents  = (const float*)d_in[1];   // (C, K, 16) f32
  const float* W      = (const float*)d_in[2];   // (512, 512) f32

  float* out = (float*)d_out;
  float* negout   = out + (size_t)NB * NDOUT;            // (B, C)
  float* codefout = negout + (size_t)NB * NC;            // (B, C) as float

  unsigned short* Wt      = (unsigned short*)d_ws;                          // 512 KiB
  unsigned short* centsH  = (unsigned short*)((char*)d_ws + 512 * 1024);    // 256 KiB
  unsigned short* centsP4 = (unsigned short*)((char*)d_ws + (1 << 20));     // 512 KiB
  float* T_neg            = (float*)((char*)d_ws + 2 * (1 << 20));          // 4 MiB
  int* T_code             = (int*)((char*)d_ws + 6 * (1 << 20));            // 4 MiB

  k_prep<<<288, 256, 0, stream>>>(W, cents, Wt, centsH, centsP4);
  k_score<<<dim3(NB / 256, NC), 256, 0, stream>>>(inputs, centsP4, cents, T_neg, T_code);
  k_finish<<<NB / 64, 256, 0, stream>>>(T_neg, T_code, negout, codefout);
  k_gemm<<<dim3(NB / 128, NDOUT / 128), 256, 0, stream>>>(centsH, T_code, Wt, out);
}

// Round 18
// 99.653 us; speedup vs baseline: 1.0647x; 1.0047x over previous
//
#include <hip/hip_runtime.h>

// DPQ network:
//  k_score : response argmax via FULL-split bf16 MFMA ((ah+al)(bh+bl));
//            64 b's per wave (4 subtile chains A-D); areg[8]+prefetch reload;
//            owner xr row early-issued (tail latency hidden); cvt_pk B-prep;
//            med3 pair tracking; setprio(1); CERT=0.001 + inline exact rescue
//  k_finish: pure tile-transpose [c][b] -> [b][c]
//  k_gemm  : codebook-gather GEMM (bf16 MFMA), reads T_code directly
// B=32768, C=32, K=256, D_SUB=16, D_IN=512, D_OUT=512

#define NB 32768
#define NC 32
#define NK 256
#define NDS 16
#define NDIN 512
#define NDOUT 512
#define CERT 0.001f

typedef __attribute__((ext_vector_type(8))) short s8v;          // 8 bf16
typedef __attribute__((ext_vector_type(4))) float f4v;          // MFMA acc
typedef __attribute__((ext_vector_type(4))) unsigned int u4v;   // 4 u32 = 8 bf16

__device__ __forceinline__ unsigned short f2bf(float f) {
  unsigned int u = __float_as_uint(f);
  u += 0x7fffu + ((u >> 16) & 1u);   // RNE
  return (unsigned short)(u >> 16);
}
__device__ __forceinline__ float bf2f(unsigned short h) {
  return __uint_as_float(((unsigned int)h) << 16);
}

// packed f32->bf16 (RNE), 2 values per instruction
#define CVTPK(d, lo, hi) \
  asm("v_cvt_pk_bf16_f32 %0, %1, %2" : "=v"(d) : "v"(lo), "v"(hi))

__device__ __forceinline__ void gload16(const void* g, void* l) {
  __builtin_amdgcn_global_load_lds(
      (const __attribute__((address_space(1))) void*)g,
      (__attribute__((address_space(3))) void*)l, 16, 0, 0);
}

// exact f32 dot over 16 dims, sequential fold (same association everywhere)
__device__ __forceinline__ float dot16(const float* x, const float* cj) {
  float4 a0 = *(const float4*)(x + 0),  a1 = *(const float4*)(x + 4);
  float4 a2 = *(const float4*)(x + 8),  a3 = *(const float4*)(x + 12);
  float4 c0 = *(const float4*)(cj + 0), c1 = *(const float4*)(cj + 4);
  float4 c2 = *(const float4*)(cj + 8), c3 = *(const float4*)(cj + 12);
  float s = a0.x * c0.x;
  s = fmaf(a0.y, c0.y, s); s = fmaf(a0.z, c0.z, s); s = fmaf(a0.w, c0.w, s);
  s = fmaf(a1.x, c1.x, s); s = fmaf(a1.y, c1.y, s); s = fmaf(a1.z, c1.z, s); s = fmaf(a1.w, c1.w, s);
  s = fmaf(a2.x, c2.x, s); s = fmaf(a2.y, c2.y, s); s = fmaf(a2.z, c2.z, s); s = fmaf(a2.w, c2.w, s);
  s = fmaf(a3.x, c3.x, s); s = fmaf(a3.y, c3.y, s); s = fmaf(a3.z, c3.z, s); s = fmaf(a3.w, c3.w, s);
  return s;
}

// exact f32 dot with preloaded x registers
__device__ __forceinline__ float dot16r(float4 a0, float4 a1, float4 a2, float4 a3,
                                        const float* cj) {
  float4 c0 = *(const float4*)(cj + 0), c1 = *(const float4*)(cj + 4);
  float4 c2 = *(const float4*)(cj + 8), c3 = *(const float4*)(cj + 12);
  float s = a0.x * c0.x;
  s = fmaf(a0.y, c0.y, s); s = fmaf(a0.z, c0.z, s); s = fmaf(a0.w, c0.w, s);
  s = fmaf(a1.x, c1.x, s); s = fmaf(a1.y, c1.y, s); s = fmaf(a1.z, c1.z, s); s = fmaf(a1.w, c1.w, s);
  s = fmaf(a2.x, c2.x, s); s = fmaf(a2.y, c2.y, s); s = fmaf(a2.z, c2.z, s); s = fmaf(a2.w, c2.w, s);
  s = fmaf(a3.x, c3.x, s); s = fmaf(a3.y, c3.y, s); s = fmaf(a3.z, c3.z, s); s = fmaf(a3.w, c3.w, s);
  return s;
}

// ---------------------------------------------------------------------------
// Kernel 0: Wt[n][k] = bf16(W[k][n]); centsH = flat bf16 (gemm gather source);
//           centsP4[c][plane][k][8]: plane 0 hi d0-7, 1 hi d8-15, 2 lo d0-7,
//           3 lo d8-15 (A-fragment order)
// ---------------------------------------------------------------------------
__global__ __launch_bounds__(256) void k_prep(const float* __restrict__ W,
                                              const float* __restrict__ cents,
                                              unsigned short* __restrict__ Wt,
                                              unsigned short* __restrict__ centsH,
                                              unsigned short* __restrict__ centsP4) {
  const int t = threadIdx.x;
  const int bid = blockIdx.x;
  if (bid < 256) {
    __shared__ float tile[32][33];
    const int k0 = (bid >> 4) << 5;
    const int n0 = (bid & 15) << 5;
    const int tx = t & 31, ty = t >> 5;
#pragma unroll
    for (int i = 0; i < 4; ++i) {
      int r = ty + i * 8;
      tile[r][tx] = W[(size_t)(k0 + r) * NDOUT + n0 + tx];
    }
    __syncthreads();
#pragma unroll
    for (int i = 0; i < 4; ++i) {
      int r = ty + i * 8;
      Wt[(size_t)(n0 + r) * NDIN + k0 + tx] = f2bf(tile[tx][r]);
    }
  } else {
    // per-c codebook processing: c = bid-256, thread t = k
    const int c = bid - 256;
    const int k = t;
    const float* src = cents + ((size_t)c * NK + k) * NDS;
    unsigned short hi[16], lo[16];
#pragma unroll
    for (int j = 0; j < 4; ++j) {
      float4 v = *(const float4*)(src + j * 4);
      unsigned short h0 = f2bf(v.x), h1 = f2bf(v.y), h2 = f2bf(v.z), h3 = f2bf(v.w);
      hi[j * 4 + 0] = h0; hi[j * 4 + 1] = h1; hi[j * 4 + 2] = h2; hi[j * 4 + 3] = h3;
      lo[j * 4 + 0] = f2bf(v.x - bf2f(h0));
      lo[j * 4 + 1] = f2bf(v.y - bf2f(h1));
      lo[j * 4 + 2] = f2bf(v.z - bf2f(h2));
      lo[j * 4 + 3] = f2bf(v.w - bf2f(h3));
    }
    unsigned short* hf = centsH + ((size_t)c * NK + k) * NDS;
#pragma unroll
    for (int j = 0; j < 4; ++j)
      *(ushort4*)(hf + j * 4) = make_ushort4(hi[j * 4], hi[j * 4 + 1], hi[j * 4 + 2], hi[j * 4 + 3]);
    unsigned short* pb = centsP4 + (size_t)c * 8192 + k * 8;
    *(ushort4*)(pb + 0 * 2048 + 0) = make_ushort4(hi[0], hi[1], hi[2], hi[3]);
    *(ushort4*)(pb + 0 * 2048 + 4) = make_ushort4(hi[4], hi[5], hi[6], hi[7]);
    *(ushort4*)(pb + 1 * 2048 + 0) = make_ushort4(hi[8], hi[9], hi[10], hi[11]);
    *(ushort4*)(pb + 1 * 2048 + 4) = make_ushort4(hi[12], hi[13], hi[14], hi[15]);
    *(ushort4*)(pb + 2 * 2048 + 0) = make_ushort4(lo[0], lo[1], lo[2], lo[3]);
    *(ushort4*)(pb + 2 * 2048 + 4) = make_ushort4(lo[4], lo[5], lo[6], lo[7]);
    *(ushort4*)(pb + 3 * 2048 + 0) = make_ushort4(lo[8], lo[9], lo[10], lo[11]);
    *(ushort4*)(pb + 3 * 2048 + 4) = make_ushort4(lo[12], lo[13], lo[14], lo[15]);
  }
}

// build hi-packed s8v + residuals from 8 f32 (u0,u1)
__device__ __forceinline__ void split8(float4 u0, float4 u1, s8v& bh, s8v& bl) {
  unsigned int ph0, ph1, ph2, ph3;
  CVTPK(ph0, u0.x, u0.y); CVTPK(ph1, u0.z, u0.w);
  CVTPK(ph2, u1.x, u1.y); CVTPK(ph3, u1.z, u1.w);
  bh = __builtin_bit_cast(s8v, (u4v){ph0, ph1, ph2, ph3});
  float ra = u0.x - __uint_as_float(ph0 << 16);
  float rb = u0.y - __uint_as_float(ph0 & 0xFFFF0000u);
  float rc = u0.z - __uint_as_float(ph1 << 16);
  float rd = u0.w - __uint_as_float(ph1 & 0xFFFF0000u);
  float re = u1.x - __uint_as_float(ph2 << 16);
  float rf = u1.y - __uint_as_float(ph2 & 0xFFFF0000u);
  float rg = u1.z - __uint_as_float(ph3 << 16);
  float rh = u1.w - __uint_as_float(ph3 & 0xFFFF0000u);
  unsigned int pl0, pl1, pl2, pl3;
  CVTPK(pl0, ra, rb); CVTPK(pl1, rc, rd);
  CVTPK(pl2, re, rf); CVTPK(pl3, rg, rh);
  bl = __builtin_bit_cast(s8v, (u4v){pl0, pl1, pl2, pl3});
}

// track a pair of adjacent-k scores (kc0, kc0+1): ~8 VALU ops / 2 scores.
#define TRACK2(v0, v1, kc0, best, sec, bk)                     \
  {                                                            \
    float vm_ = fmaxf(v0, v1);                                 \
    float md_ = __builtin_amdgcn_fmed3f(best, v0, v1);         \
    sec = fmaxf(sec, md_);                                     \
    int km_ = (v1 > v0) ? (kc0 + 1) : (kc0);                   \
    bool gt_ = vm_ > best;                                     \
    bk = gt_ ? km_ : bk;                                       \
    best = fmaxf(best, vm_);                                   \
  }

// MFMA pair + tracking for one chain at one kt
#define CHAIN_STEP(a, p1, p2, kc, best, sec, bk)                             \
  {                                                                          \
    f4v acc_ = __builtin_amdgcn_mfma_f32_16x16x32_bf16(a, p1, zz, 0, 0, 0);  \
    acc_ = __builtin_amdgcn_mfma_f32_16x16x32_bf16(a, p2, acc_, 0, 0, 0);    \
    TRACK2(acc_[0], acc_[1], kc + 0, best, sec, bk)                          \
    TRACK2(acc_[2], acc_[3], kc + 2, best, sec, bk)                          \
  }

// butterfly-combine one chain across the 4 lane-groups
#define BFLY(best, sec, bk)                                    \
  {                                                            \
    _Pragma("unroll")                                          \
    for (int off = 16; off <= 32; off <<= 1) {                 \
      float vb = __shfl_xor(best, off);                        \
      float sb = __shfl_xor(sec, off);                         \
      int kb = __shfl_xor(bk, off);                            \
      float mn = fminf(best, vb);                              \
      sec = fmaxf(fmaxf(sec, sb), mn);                         \
      bool take = (vb > best) || (vb == best && kb < bk);      \
      bk = take ? kb : bk;                                     \
      best = fmaxf(best, vb);                                  \
    }                                                          \
  }

// ---------------------------------------------------------------------------
// k_score: per wave = 64 b's x 1 c (4 subtile chains). B-loads + owner xr
// issued first; areg[8] + prefetch reload; FULL-split pairing per chain;
// setprio(1) around main loop. Lane l finalizes b = b0 + l.
// ---------------------------------------------------------------------------
__global__ __launch_bounds__(256, 4) void k_score(const float* __restrict__ inputs,
                                                  const unsigned short* __restrict__ centsP4,
                                                  const float* __restrict__ cents,
                                                  float* __restrict__ T_neg,
                                                  int* __restrict__ T_code) {
  const int t = threadIdx.x;
  const int l = t & 63;
  const int w = t >> 6;
  const int c = blockIdx.y;
  const int b0 = blockIdx.x * 256 + w * 64;   // this wave: b0..b0+63 (4 subtiles)
  const int g = l >> 4;
  const int col = l & 15;
  const int dh = (g & 1) * 8;
  const int g4 = g * 4;

  // ---- issue B-row loads first (latency overlaps the A-burst issue)
  const float* r0 = inputs + ((size_t)(b0 + col) * NC + c) * NDS + dh;
  const float* r1 = inputs + ((size_t)(b0 + 16 + col) * NC + c) * NDS + dh;
  const float* r2 = inputs + ((size_t)(b0 + 32 + col) * NC + c) * NDS + dh;
  const float* r3 = inputs + ((size_t)(b0 + 48 + col) * NC + c) * NDS + dh;
  float4 uA0 = *(const float4*)(r0), uA1 = *(const float4*)(r0 + 4);
  float4 uB0 = *(const float4*)(r1), uB1 = *(const float4*)(r1 + 4);
  float4 uC0 = *(const float4*)(r2), uC1 = *(const float4*)(r2 + 4);
  float4 uD0 = *(const float4*)(r3), uD1 = *(const float4*)(r3 + 4);

  // ---- early-issue owner's full xr row (finalize dot16 input; hidden latency)
  const float* xrp = inputs + ((size_t)(b0 + l) * NC + c) * NDS;
  float4 x0 = *(const float4*)(xrp + 0), x1 = *(const float4*)(xrp + 4);
  float4 x2 = *(const float4*)(xrp + 8), x3 = *(const float4*)(xrp + 12);

  // ---- first 8 A-fragments (independent 16B loads)
  const unsigned short* abase = centsP4 + (size_t)c * 8192 + g * 2048 + col * 8;
  s8v areg[8];
#pragma unroll
  for (int kt = 0; kt < 8; ++kt)
    areg[kt] = *(const s8v*)(abase + kt * 128);

  // ---- B fragments (4 subtiles), hi/lo split via cvt_pk; full-split pairing
  s8v p1A, p2A, p1B, p2B, p1C, p2C, p1D, p2D;
  {
    s8v bh, bl;
    const bool hiLane = (l < 32);             // kappa 0-15 lanes
    split8(uA0, uA1, bh, bl); p1A = hiLane ? bh : bl; p2A = hiLane ? bl : bh;
    split8(uB0, uB1, bh, bl); p1B = hiLane ? bh : bl; p2B = hiLane ? bl : bh;
    split8(uC0, uC1, bh, bl); p1C = hiLane ? bh : bl; p2C = hiLane ? bl : bh;
    split8(uD0, uD1, bh, bl); p1D = hiLane ? bh : bl; p2D = hiLane ? bl : bh;
  }

  float bestA = -3.0e38f, secA = -3.0e38f;
  float bestB = -3.0e38f, secB = -3.0e38f;
  float bestC = -3.0e38f, secC = -3.0e38f;
  float bestD = -3.0e38f, secD = -3.0e38f;
  int bkA = 0, bkB = 0, bkC = 0, bkD = 0;
  const f4v zz = {0.0f, 0.0f, 0.0f, 0.0f};

  __builtin_amdgcn_s_setprio(1);
#pragma unroll
  for (int kt = 0; kt < 8; ++kt) {
    s8v a = areg[kt];
    areg[kt] = *(const s8v*)(abase + (kt + 8) * 128);   // prefetch kt+8
    const int kc = kt * 16;
    CHAIN_STEP(a, p1A, p2A, kc, bestA, secA, bkA)
    CHAIN_STEP(a, p1B, p2B, kc, bestB, secB, bkB)
    CHAIN_STEP(a, p1C, p2C, kc, bestC, secC, bkC)
    CHAIN_STEP(a, p1D, p2D, kc, bestD, secD, bkD)
  }
#pragma unroll
  for (int kt = 8; kt < 16; ++kt) {
    s8v a = areg[kt - 8];
    const int kc = kt * 16;
    CHAIN_STEP(a, p1A, p2A, kc, bestA, secA, bkA)
    CHAIN_STEP(a, p1B, p2B, kc, bestB, secB, bkB)
    CHAIN_STEP(a, p1C, p2C, kc, bestC, secC, bkC)
    CHAIN_STEP(a, p1D, p2D, kc, bestD, secD, bkD)
  }
  __builtin_amdgcn_s_setprio(0);

  bkA += g4; bkB += g4; bkC += g4; bkD += g4;

  BFLY(bestA, secA, bkA)
  BFLY(bestB, secB, bkB)
  BFLY(bestC, secC, bkC)
  BFLY(bestD, secD, bkD)

  // finalize: lane l owns b = b0 + l (chain = l>>4)
  float best = (g == 0) ? bestA : (g == 1) ? bestB : (g == 2) ? bestC : bestD;
  float sec  = (g == 0) ? secA  : (g == 1) ? secB  : (g == 2) ? secC  : secD;
  int bk     = (g == 0) ? bkA   : (g == 1) ? bkB   : (g == 2) ? bkC   : bkD;
  const bool flagged = (best - sec <= CERT);

  if (!flagged) {
    const int b = b0 + l;
    const float* cr = cents + ((size_t)c * NK + bk) * NDS;
    size_t o = (size_t)c * NB + b;
    T_neg[o] = dot16r(x0, x1, x2, x3, cr);
    T_code[o] = bk;
  }

  // inline rescue: whole wave rescans flagged entries exactly
  unsigned long long mask = __ballot(flagged);
  while (mask) {
    const int p = __builtin_ctzll(mask);
    mask &= mask - 1;
    const int b = b0 + p;
    const float* xr = inputs + ((size_t)b * NC + c) * NDS;
    const float* cr = cents + ((size_t)c * NK + l * 4) * NDS;
    float rb = -3.0e38f;
    int rk = 0;
#pragma unroll
    for (int q = 0; q < 4; ++q) {
      float d = dot16(xr, cr + q * NDS);
      if (d > rb) { rb = d; rk = l * 4 + q; }   // strict >, ascending k
    }
#pragma unroll
    for (int off = 1; off <= 32; off <<= 1) {
      float vb = __shfl_xor(rb, off);
      int kb = __shfl_xor(rk, off);
      bool take = (vb > rb) || (vb == rb && kb < rk);
      rb = take ? vb : rb;
      rk = take ? kb : rk;
    }
    if (l == 0) {
      size_t o = (size_t)c * NB + b;
      T_neg[o] = rb;
      T_code[o] = rk;
    }
  }
}

// ---------------------------------------------------------------------------
// k_finish: pure transpose of negout/codefout
// ---------------------------------------------------------------------------
__global__ __launch_bounds__(256) void k_finish(const float* __restrict__ T_neg,
                                                const int* __restrict__ T_code,
                                                float* __restrict__ negout,
                                                float* __restrict__ codefout) {
  __shared__ float sneg[64][33];
  __shared__ int scode[64][33];
  const int t = threadIdx.x;
  const int b0 = blockIdx.x * 64;

#pragma unroll
  for (int it = 0; it < 8; ++it) {
    int lin = it * 256 + t;
    int c = lin >> 6, bi = lin & 63;
    sneg[bi][c] = T_neg[(size_t)c * NB + b0 + bi];
    scode[bi][c] = T_code[(size_t)c * NB + b0 + bi];
  }
  __syncthreads();

#pragma unroll
  for (int it = 0; it < 8; ++it) {
    int lin = it * 256 + t;
    int bi = lin >> 5, c = lin & 31;
    size_t o = (size_t)(b0 + bi) * NC + c;
    negout[o] = -sneg[bi][c];
    codefout[o] = (float)scode[bi][c];
  }
}

// ---------------------------------------------------------------------------
// Kernel 2: product = gather(centsH, codes) @ W  via bf16 MFMA.
// Codes read directly from T_code[c][b] (coalesced 512B segments per c).
// ---------------------------------------------------------------------------
__global__ __launch_bounds__(256) void k_gemm(const unsigned short* __restrict__ centsB,
                                              const int* __restrict__ T_code,
                                              const unsigned short* __restrict__ Wt,
                                              float* __restrict__ out) {
  __shared__ __align__(16) unsigned short As[128 * 64];
  __shared__ __align__(16) unsigned short Bs[128 * 64];
  __shared__ int lcode[128 * 33];

  const int t = threadIdx.x;
  const int l = t & 63;
  const int w = t >> 6;
  const int wm = w >> 1, wn = w & 1;
  const int m0 = blockIdx.x * 128;
  const int n0 = blockIdx.y * 128;

  {
    // lcode[row][col] = T_code[col*NB + m0 + row]
    const int cc = t >> 3;          // 0..31
    const int ch = t & 7;           // 0..7 -> rows ch*16..ch*16+15
#pragma unroll
    for (int i = 0; i < 4; ++i) {
      int row0 = ch * 16 + i * 4;
      int4 v = *(const int4*)(T_code + (size_t)cc * NB + m0 + row0);
      lcode[(row0 + 0) * 33 + cc] = v.x;
      lcode[(row0 + 1) * 33 + cc] = v.y;
      lcode[(row0 + 2) * 33 + cc] = v.z;
      lcode[(row0 + 3) * 33 + cc] = v.w;
    }
  }

  f4v acc[4][4] = {};
  const int s = t & 7;
  const int rq = t >> 3;

  for (int kt = 0; kt < 8; ++kt) {
    __syncthreads();
    const int c0 = kt * 4;
#pragma unroll
    for (int i = 0; i < 4; ++i) {
      int lr = i * 32 + rq;
      int srcslot = s ^ (lr & 7);
      int cl = srcslot >> 1, half = srcslot & 1;
      int code = lcode[lr * 33 + c0 + cl];
      const unsigned short* gsrc =
          centsB + ((size_t)((c0 + cl) * NK + code) * NDS + half * 8);
      gload16(gsrc, (char*)As + i * 4096 + (w << 10));
    }
#pragma unroll
    for (int i = 0; i < 4; ++i) {
      int lr = i * 32 + rq;
      int k16 = s ^ (lr & 7);
      const unsigned short* gsrc = Wt + (size_t)(n0 + lr) * NDIN + kt * 64 + k16 * 8;
      gload16(gsrc, (char*)Bs + i * 4096 + (w << 10));
    }
    __syncthreads();

    s8v af[4][2], bfr[4][2];
#pragma unroll
    for (int mf = 0; mf < 4; ++mf)
#pragma unroll
      for (int ks = 0; ks < 2; ++ks) {
        int row = wm * 64 + mf * 16 + (l & 15);
        int slot = ks * 4 + (l >> 4);
        af[mf][ks] = *(const s8v*)((const char*)As + row * 128 + ((slot ^ (row & 7)) << 4));
      }
#pragma unroll
    for (int nf = 0; nf < 4; ++nf)
#pragma unroll
      for (int ks = 0; ks < 2; ++ks) {
        int row = wn * 64 + nf * 16 + (l & 15);
        int slot = ks * 4 + (l >> 4);
        bfr[nf][ks] = *(const s8v*)((const char*)Bs + row * 128 + ((slot ^ (row & 7)) << 4));
      }
#pragma unroll
    for (int ks = 0; ks < 2; ++ks)
#pragma unroll
      for (int mf = 0; mf < 4; ++mf)
#pragma unroll
        for (int nf = 0; nf < 4; ++nf)
          acc[mf][nf] = __builtin_amdgcn_mfma_f32_16x16x32_bf16(
              af[mf][ks], bfr[nf][ks], acc[mf][nf], 0, 0, 0);
  }

#pragma unroll
  for (int mf = 0; mf < 4; ++mf)
#pragma unroll
    for (int nf = 0; nf < 4; ++nf)
#pragma unroll
      for (int r = 0; r < 4; ++r) {
        int row = m0 + wm * 64 + mf * 16 + (l >> 4) * 4 + r;
        int col = n0 + wn * 64 + nf * 16 + (l & 15);
        out[(size_t)row * NDOUT + col] = acc[mf][nf][r];
      }
}

// ---------------------------------------------------------------------------
extern "C" void kernel_launch(void* const* d_in, const int* in_sizes, int n_in,
                              void* d_out, int out_size, void* d_ws, size_t ws_size,
                              hipStream_t stream) {
  const float* inputs = (const float*)d_in[0];   // (B, C, 16) f32
  const float* cents  = (const float*)d_in[1];   // (C, K, 16) f32
  const float* W      = (const float*)d_in[2];   // (512, 512) f32

  float* out = (float*)d_out;
  float* negout   = out + (size_t)NB * NDOUT;            // (B, C)
  float* codefout = negout + (size_t)NB * NC;            // (B, C) as float

  unsigned short* Wt      = (unsigned short*)d_ws;                          // 512 KiB
  unsigned short* centsH  = (unsigned short*)((char*)d_ws + 512 * 1024);    // 256 KiB
  unsigned short* centsP4 = (unsigned short*)((char*)d_ws + (1 << 20));     // 512 KiB
  float* T_neg            = (float*)((char*)d_ws + 2 * (1 << 20));          // 4 MiB
  int* T_code             = (int*)((char*)d_ws + 6 * (1 << 20));            // 4 MiB

  k_prep<<<288, 256, 0, stream>>>(W, cents, Wt, centsH, centsP4);
  k_score<<<dim3(NB / 256, NC), 256, 0, stream>>>(inputs, centsP4, cents, T_neg, T_code);
  k_finish<<<NB / 64, 256, 0, stream>>>(T_neg, T_code, negout, codefout);
  k_gemm<<<dim3(NB / 128, NDOUT / 128), 256, 0, stream>>>(centsH, T_code, Wt, out);
}

// Round 19
// 98.322 us; speedup vs baseline: 1.0791x; 1.0135x over previous
//
#include <hip/hip_runtime.h>

// DPQ network:
//  k_score : response argmax via FULL-split bf16 MFMA ((ah+al)(bh+bl));
//            64 b's per wave (4 subtile chains A-D); areg[8]+prefetch reload;
//            owner xr row early-issued; cvt_pk B-prep; med3 pair tracking;
//            setprio(1); CERT=0.001 + inline exact rescue  (R18 verbatim)
//  k_gemm  : codebook-gather GEMM (bf16 MFMA) + y==4 transpose layer
//            (k_finish folded in as dedicated blocks; overlaps with GEMM)
// B=32768, C=32, K=256, D_SUB=16, D_IN=512, D_OUT=512

#define NB 32768
#define NC 32
#define NK 256
#define NDS 16
#define NDIN 512
#define NDOUT 512
#define CERT 0.001f

typedef __attribute__((ext_vector_type(8))) short s8v;          // 8 bf16
typedef __attribute__((ext_vector_type(4))) float f4v;          // MFMA acc
typedef __attribute__((ext_vector_type(4))) unsigned int u4v;   // 4 u32 = 8 bf16

__device__ __forceinline__ unsigned short f2bf(float f) {
  unsigned int u = __float_as_uint(f);
  u += 0x7fffu + ((u >> 16) & 1u);   // RNE
  return (unsigned short)(u >> 16);
}
__device__ __forceinline__ float bf2f(unsigned short h) {
  return __uint_as_float(((unsigned int)h) << 16);
}

// packed f32->bf16 (RNE), 2 values per instruction
#define CVTPK(d, lo, hi) \
  asm("v_cvt_pk_bf16_f32 %0, %1, %2" : "=v"(d) : "v"(lo), "v"(hi))

__device__ __forceinline__ void gload16(const void* g, void* l) {
  __builtin_amdgcn_global_load_lds(
      (const __attribute__((address_space(1))) void*)g,
      (__attribute__((address_space(3))) void*)l, 16, 0, 0);
}

// exact f32 dot over 16 dims, sequential fold (same association everywhere)
__device__ __forceinline__ float dot16(const float* x, const float* cj) {
  float4 a0 = *(const float4*)(x + 0),  a1 = *(const float4*)(x + 4);
  float4 a2 = *(const float4*)(x + 8),  a3 = *(const float4*)(x + 12);
  float4 c0 = *(const float4*)(cj + 0), c1 = *(const float4*)(cj + 4);
  float4 c2 = *(const float4*)(cj + 8), c3 = *(const float4*)(cj + 12);
  float s = a0.x * c0.x;
  s = fmaf(a0.y, c0.y, s); s = fmaf(a0.z, c0.z, s); s = fmaf(a0.w, c0.w, s);
  s = fmaf(a1.x, c1.x, s); s = fmaf(a1.y, c1.y, s); s = fmaf(a1.z, c1.z, s); s = fmaf(a1.w, c1.w, s);
  s = fmaf(a2.x, c2.x, s); s = fmaf(a2.y, c2.y, s); s = fmaf(a2.z, c2.z, s); s = fmaf(a2.w, c2.w, s);
  s = fmaf(a3.x, c3.x, s); s = fmaf(a3.y, c3.y, s); s = fmaf(a3.z, c3.z, s); s = fmaf(a3.w, c3.w, s);
  return s;
}

// exact f32 dot with preloaded x registers
__device__ __forceinline__ float dot16r(float4 a0, float4 a1, float4 a2, float4 a3,
                                        const float* cj) {
  float4 c0 = *(const float4*)(cj + 0), c1 = *(const float4*)(cj + 4);
  float4 c2 = *(const float4*)(cj + 8), c3 = *(const float4*)(cj + 12);
  float s = a0.x * c0.x;
  s = fmaf(a0.y, c0.y, s); s = fmaf(a0.z, c0.z, s); s = fmaf(a0.w, c0.w, s);
  s = fmaf(a1.x, c1.x, s); s = fmaf(a1.y, c1.y, s); s = fmaf(a1.z, c1.z, s); s = fmaf(a1.w, c1.w, s);
  s = fmaf(a2.x, c2.x, s); s = fmaf(a2.y, c2.y, s); s = fmaf(a2.z, c2.z, s); s = fmaf(a2.w, c2.w, s);
  s = fmaf(a3.x, c3.x, s); s = fmaf(a3.y, c3.y, s); s = fmaf(a3.z, c3.z, s); s = fmaf(a3.w, c3.w, s);
  return s;
}

// ---------------------------------------------------------------------------
// Kernel 0: Wt[n][k] = bf16(W[k][n]); centsH = flat bf16 (gemm gather source);
//           centsP4[c][plane][k][8]: plane 0 hi d0-7, 1 hi d8-15, 2 lo d0-7,
//           3 lo d8-15 (A-fragment order)
// ---------------------------------------------------------------------------
__global__ __launch_bounds__(256) void k_prep(const float* __restrict__ W,
                                              const float* __restrict__ cents,
                                              unsigned short* __restrict__ Wt,
                                              unsigned short* __restrict__ centsH,
                                              unsigned short* __restrict__ centsP4) {
  const int t = threadIdx.x;
  const int bid = blockIdx.x;
  if (bid < 256) {
    __shared__ float tile[32][33];
    const int k0 = (bid >> 4) << 5;
    const int n0 = (bid & 15) << 5;
    const int tx = t & 31, ty = t >> 5;
#pragma unroll
    for (int i = 0; i < 4; ++i) {
      int r = ty + i * 8;
      tile[r][tx] = W[(size_t)(k0 + r) * NDOUT + n0 + tx];
    }
    __syncthreads();
#pragma unroll
    for (int i = 0; i < 4; ++i) {
      int r = ty + i * 8;
      Wt[(size_t)(n0 + r) * NDIN + k0 + tx] = f2bf(tile[tx][r]);
    }
  } else {
    // per-c codebook processing: c = bid-256, thread t = k
    const int c = bid - 256;
    const int k = t;
    const float* src = cents + ((size_t)c * NK + k) * NDS;
    unsigned short hi[16], lo[16];
#pragma unroll
    for (int j = 0; j < 4; ++j) {
      float4 v = *(const float4*)(src + j * 4);
      unsigned short h0 = f2bf(v.x), h1 = f2bf(v.y), h2 = f2bf(v.z), h3 = f2bf(v.w);
      hi[j * 4 + 0] = h0; hi[j * 4 + 1] = h1; hi[j * 4 + 2] = h2; hi[j * 4 + 3] = h3;
      lo[j * 4 + 0] = f2bf(v.x - bf2f(h0));
      lo[j * 4 + 1] = f2bf(v.y - bf2f(h1));
      lo[j * 4 + 2] = f2bf(v.z - bf2f(h2));
      lo[j * 4 + 3] = f2bf(v.w - bf2f(h3));
    }
    unsigned short* hf = centsH + ((size_t)c * NK + k) * NDS;
#pragma unroll
    for (int j = 0; j < 4; ++j)
      *(ushort4*)(hf + j * 4) = make_ushort4(hi[j * 4], hi[j * 4 + 1], hi[j * 4 + 2], hi[j * 4 + 3]);
    unsigned short* pb = centsP4 + (size_t)c * 8192 + k * 8;
    *(ushort4*)(pb + 0 * 2048 + 0) = make_ushort4(hi[0], hi[1], hi[2], hi[3]);
    *(ushort4*)(pb + 0 * 2048 + 4) = make_ushort4(hi[4], hi[5], hi[6], hi[7]);
    *(ushort4*)(pb + 1 * 2048 + 0) = make_ushort4(hi[8], hi[9], hi[10], hi[11]);
    *(ushort4*)(pb + 1 * 2048 + 4) = make_ushort4(hi[12], hi[13], hi[14], hi[15]);
    *(ushort4*)(pb + 2 * 2048 + 0) = make_ushort4(lo[0], lo[1], lo[2], lo[3]);
    *(ushort4*)(pb + 2 * 2048 + 4) = make_ushort4(lo[4], lo[5], lo[6], lo[7]);
    *(ushort4*)(pb + 3 * 2048 + 0) = make_ushort4(lo[8], lo[9], lo[10], lo[11]);
    *(ushort4*)(pb + 3 * 2048 + 4) = make_ushort4(lo[12], lo[13], lo[14], lo[15]);
  }
}

// build hi-packed s8v + residuals from 8 f32 (u0,u1)
__device__ __forceinline__ void split8(float4 u0, float4 u1, s8v& bh, s8v& bl) {
  unsigned int ph0, ph1, ph2, ph3;
  CVTPK(ph0, u0.x, u0.y); CVTPK(ph1, u0.z, u0.w);
  CVTPK(ph2, u1.x, u1.y); CVTPK(ph3, u1.z, u1.w);
  bh = __builtin_bit_cast(s8v, (u4v){ph0, ph1, ph2, ph3});
  float ra = u0.x - __uint_as_float(ph0 << 16);
  float rb = u0.y - __uint_as_float(ph0 & 0xFFFF0000u);
  float rc = u0.z - __uint_as_float(ph1 << 16);
  float rd = u0.w - __uint_as_float(ph1 & 0xFFFF0000u);
  float re = u1.x - __uint_as_float(ph2 << 16);
  float rf = u1.y - __uint_as_float(ph2 & 0xFFFF0000u);
  float rg = u1.z - __uint_as_float(ph3 << 16);
  float rh = u1.w - __uint_as_float(ph3 & 0xFFFF0000u);
  unsigned int pl0, pl1, pl2, pl3;
  CVTPK(pl0, ra, rb); CVTPK(pl1, rc, rd);
  CVTPK(pl2, re, rf); CVTPK(pl3, rg, rh);
  bl = __builtin_bit_cast(s8v, (u4v){pl0, pl1, pl2, pl3});
}

// track a pair of adjacent-k scores (kc0, kc0+1): ~8 VALU ops / 2 scores.
#define TRACK2(v0, v1, kc0, best, sec, bk)                     \
  {                                                            \
    float vm_ = fmaxf(v0, v1);                                 \
    float md_ = __builtin_amdgcn_fmed3f(best, v0, v1);         \
    sec = fmaxf(sec, md_);                                     \
    int km_ = (v1 > v0) ? (kc0 + 1) : (kc0);                   \
    bool gt_ = vm_ > best;                                     \
    bk = gt_ ? km_ : bk;                                       \
    best = fmaxf(best, vm_);                                   \
  }

// MFMA pair + tracking for one chain at one kt
#define CHAIN_STEP(a, p1, p2, kc, best, sec, bk)                             \
  {                                                                          \
    f4v acc_ = __builtin_amdgcn_mfma_f32_16x16x32_bf16(a, p1, zz, 0, 0, 0);  \
    acc_ = __builtin_amdgcn_mfma_f32_16x16x32_bf16(a, p2, acc_, 0, 0, 0);    \
    TRACK2(acc_[0], acc_[1], kc + 0, best, sec, bk)                          \
    TRACK2(acc_[2], acc_[3], kc + 2, best, sec, bk)                          \
  }

// butterfly-combine one chain across the 4 lane-groups
#define BFLY(best, sec, bk)                                    \
  {                                                            \
    _Pragma("unroll")                                          \
    for (int off = 16; off <= 32; off <<= 1) {                 \
      float vb = __shfl_xor(best, off);                        \
      float sb = __shfl_xor(sec, off);                         \
      int kb = __shfl_xor(bk, off);                            \
      float mn = fminf(best, vb);                              \
      sec = fmaxf(fmaxf(sec, sb), mn);                         \
      bool take = (vb > best) || (vb == best && kb < bk);      \
      bk = take ? kb : bk;                                     \
      best = fmaxf(best, vb);                                  \
    }                                                          \
  }

// ---------------------------------------------------------------------------
// k_score: per wave = 64 b's x 1 c (4 subtile chains). R18 verbatim.
// ---------------------------------------------------------------------------
__global__ __launch_bounds__(256, 4) void k_score(const float* __restrict__ inputs,
                                                  const unsigned short* __restrict__ centsP4,
                                                  const float* __restrict__ cents,
                                                  float* __restrict__ T_neg,
                                                  int* __restrict__ T_code) {
  const int t = threadIdx.x;
  const int l = t & 63;
  const int w = t >> 6;
  const int c = blockIdx.y;
  const int b0 = blockIdx.x * 256 + w * 64;   // this wave: b0..b0+63 (4 subtiles)
  const int g = l >> 4;
  const int col = l & 15;
  const int dh = (g & 1) * 8;
  const int g4 = g * 4;

  // ---- issue B-row loads first (latency overlaps the A-burst issue)
  const float* r0 = inputs + ((size_t)(b0 + col) * NC + c) * NDS + dh;
  const float* r1 = inputs + ((size_t)(b0 + 16 + col) * NC + c) * NDS + dh;
  const float* r2 = inputs + ((size_t)(b0 + 32 + col) * NC + c) * NDS + dh;
  const float* r3 = inputs + ((size_t)(b0 + 48 + col) * NC + c) * NDS + dh;
  float4 uA0 = *(const float4*)(r0), uA1 = *(const float4*)(r0 + 4);
  float4 uB0 = *(const float4*)(r1), uB1 = *(const float4*)(r1 + 4);
  float4 uC0 = *(const float4*)(r2), uC1 = *(const float4*)(r2 + 4);
  float4 uD0 = *(const float4*)(r3), uD1 = *(const float4*)(r3 + 4);

  // ---- early-issue owner's full xr row (finalize dot16 input; hidden latency)
  const float* xrp = inputs + ((size_t)(b0 + l) * NC + c) * NDS;
  float4 x0 = *(const float4*)(xrp + 0), x1 = *(const float4*)(xrp + 4);
  float4 x2 = *(const float4*)(xrp + 8), x3 = *(const float4*)(xrp + 12);

  // ---- first 8 A-fragments (independent 16B loads)
  const unsigned short* abase = centsP4 + (size_t)c * 8192 + g * 2048 + col * 8;
  s8v areg[8];
#pragma unroll
  for (int kt = 0; kt < 8; ++kt)
    areg[kt] = *(const s8v*)(abase + kt * 128);

  // ---- B fragments (4 subtiles), hi/lo split via cvt_pk; full-split pairing
  s8v p1A, p2A, p1B, p2B, p1C, p2C, p1D, p2D;
  {
    s8v bh, bl;
    const bool hiLane = (l < 32);             // kappa 0-15 lanes
    split8(uA0, uA1, bh, bl); p1A = hiLane ? bh : bl; p2A = hiLane ? bl : bh;
    split8(uB0, uB1, bh, bl); p1B = hiLane ? bh : bl; p2B = hiLane ? bl : bh;
    split8(uC0, uC1, bh, bl); p1C = hiLane ? bh : bl; p2C = hiLane ? bl : bh;
    split8(uD0, uD1, bh, bl); p1D = hiLane ? bh : bl; p2D = hiLane ? bl : bh;
  }

  float bestA = -3.0e38f, secA = -3.0e38f;
  float bestB = -3.0e38f, secB = -3.0e38f;
  float bestC = -3.0e38f, secC = -3.0e38f;
  float bestD = -3.0e38f, secD = -3.0e38f;
  int bkA = 0, bkB = 0, bkC = 0, bkD = 0;
  const f4v zz = {0.0f, 0.0f, 0.0f, 0.0f};

  __builtin_amdgcn_s_setprio(1);
#pragma unroll
  for (int kt = 0; kt < 8; ++kt) {
    s8v a = areg[kt];
    areg[kt] = *(const s8v*)(abase + (kt + 8) * 128);   // prefetch kt+8
    const int kc = kt * 16;
    CHAIN_STEP(a, p1A, p2A, kc, bestA, secA, bkA)
    CHAIN_STEP(a, p1B, p2B, kc, bestB, secB, bkB)
    CHAIN_STEP(a, p1C, p2C, kc, bestC, secC, bkC)
    CHAIN_STEP(a, p1D, p2D, kc, bestD, secD, bkD)
  }
#pragma unroll
  for (int kt = 8; kt < 16; ++kt) {
    s8v a = areg[kt - 8];
    const int kc = kt * 16;
    CHAIN_STEP(a, p1A, p2A, kc, bestA, secA, bkA)
    CHAIN_STEP(a, p1B, p2B, kc, bestB, secB, bkB)
    CHAIN_STEP(a, p1C, p2C, kc, bestC, secC, bkC)
    CHAIN_STEP(a, p1D, p2D, kc, bestD, secD, bkD)
  }
  __builtin_amdgcn_s_setprio(0);

  bkA += g4; bkB += g4; bkC += g4; bkD += g4;

  BFLY(bestA, secA, bkA)
  BFLY(bestB, secB, bkB)
  BFLY(bestC, secC, bkC)
  BFLY(bestD, secD, bkD)

  // finalize: lane l owns b = b0 + l (chain = l>>4)
  float best = (g == 0) ? bestA : (g == 1) ? bestB : (g == 2) ? bestC : bestD;
  float sec  = (g == 0) ? secA  : (g == 1) ? secB  : (g == 2) ? secC  : secD;
  int bk     = (g == 0) ? bkA   : (g == 1) ? bkB   : (g == 2) ? bkC   : bkD;
  const bool flagged = (best - sec <= CERT);

  if (!flagged) {
    const int b = b0 + l;
    const float* cr = cents + ((size_t)c * NK + bk) * NDS;
    size_t o = (size_t)c * NB + b;
    T_neg[o] = dot16r(x0, x1, x2, x3, cr);
    T_code[o] = bk;
  }

  // inline rescue: whole wave rescans flagged entries exactly
  unsigned long long mask = __ballot(flagged);
  while (mask) {
    const int p = __builtin_ctzll(mask);
    mask &= mask - 1;
    const int b = b0 + p;
    const float* xr = inputs + ((size_t)b * NC + c) * NDS;
    const float* cr = cents + ((size_t)c * NK + l * 4) * NDS;
    float rb = -3.0e38f;
    int rk = 0;
#pragma unroll
    for (int q = 0; q < 4; ++q) {
      float d = dot16(xr, cr + q * NDS);
      if (d > rb) { rb = d; rk = l * 4 + q; }   // strict >, ascending k
    }
#pragma unroll
    for (int off = 1; off <= 32; off <<= 1) {
      float vb = __shfl_xor(rb, off);
      int kb = __shfl_xor(rk, off);
      bool take = (vb > rb) || (vb == rb && kb < rk);
      rb = take ? vb : rb;
      rk = take ? kb : rk;
    }
    if (l == 0) {
      size_t o = (size_t)c * NB + b;
      T_neg[o] = rb;
      T_code[o] = rk;
    }
  }
}

// ---------------------------------------------------------------------------
// Kernel 2: product = gather(centsH, codes) @ W  via bf16 MFMA.
// Codes read from T_code[c][b]. blockIdx.y==4: transpose-only blocks
// (k_finish folded in; 128 b-rows each, overlaps with GEMM blocks).
// ---------------------------------------------------------------------------
__global__ __launch_bounds__(256) void k_gemm(const unsigned short* __restrict__ centsB,
                                              const int* __restrict__ T_code,
                                              const float* __restrict__ T_neg,
                                              const unsigned short* __restrict__ Wt,
                                              float* __restrict__ out,
                                              float* __restrict__ negout,
                                              float* __restrict__ codefout) {
  __shared__ __align__(16) unsigned short As[128 * 64];
  __shared__ __align__(16) unsigned short Bs[128 * 64];
  __shared__ int lcode[128 * 33];

  const int t = threadIdx.x;
  const int m0 = blockIdx.x * 128;

  if (blockIdx.y == 4) {
    // ---- transpose-only block: [c][b] -> [b][c] for rows m0..m0+127
    float* sf = (float*)As;            // 4096 floats = 128 b x 32 c
    const int cc = t >> 3;             // 0..31
    const int ch = t & 7;              // 0..7 -> rows ch*16..ch*16+15
#pragma unroll
    for (int i = 0; i < 4; ++i) {
      int row0 = ch * 16 + i * 4;
      float4 vn = *(const float4*)(T_neg + (size_t)cc * NB + m0 + row0);
      int4 vc = *(const int4*)(T_code + (size_t)cc * NB + m0 + row0);
      sf[(row0 + 0) * 32 + cc] = vn.x;
      sf[(row0 + 1) * 32 + cc] = vn.y;
      sf[(row0 + 2) * 32 + cc] = vn.z;
      sf[(row0 + 3) * 32 + cc] = vn.w;
      lcode[(row0 + 0) * 33 + cc] = vc.x;
      lcode[(row0 + 1) * 33 + cc] = vc.y;
      lcode[(row0 + 2) * 33 + cc] = vc.z;
      lcode[(row0 + 3) * 33 + cc] = vc.w;
    }
    __syncthreads();
#pragma unroll
    for (int it = 0; it < 16; ++it) {
      int lin = it * 256 + t;          // 4096 entries
      int bi = lin >> 5, c2 = lin & 31;
      size_t o = (size_t)(m0 + bi) * NC + c2;
      negout[o] = -sf[bi * 32 + c2];
      codefout[o] = (float)lcode[bi * 33 + c2];
    }
    return;
  }

  const int l = t & 63;
  const int w = t >> 6;
  const int wm = w >> 1, wn = w & 1;
  const int n0 = blockIdx.y * 128;

  {
    // lcode[row][col] = T_code[col*NB + m0 + row]
    const int cc = t >> 3;          // 0..31
    const int ch = t & 7;           // 0..7 -> rows ch*16..ch*16+15
#pragma unroll
    for (int i = 0; i < 4; ++i) {
      int row0 = ch * 16 + i * 4;
      int4 v = *(const int4*)(T_code + (size_t)cc * NB + m0 + row0);
      lcode[(row0 + 0) * 33 + cc] = v.x;
      lcode[(row0 + 1) * 33 + cc] = v.y;
      lcode[(row0 + 2) * 33 + cc] = v.z;
      lcode[(row0 + 3) * 33 + cc] = v.w;
    }
  }

  f4v acc[4][4] = {};
  const int s = t & 7;
  const int rq = t >> 3;

  for (int kt = 0; kt < 8; ++kt) {
    __syncthreads();
    const int c0 = kt * 4;
#pragma unroll
    for (int i = 0; i < 4; ++i) {
      int lr = i * 32 + rq;
      int srcslot = s ^ (lr & 7);
      int cl = srcslot >> 1, half = srcslot & 1;
      int code = lcode[lr * 33 + c0 + cl];
      const unsigned short* gsrc =
          centsB + ((size_t)((c0 + cl) * NK + code) * NDS + half * 8);
      gload16(gsrc, (char*)As + i * 4096 + (w << 10));
    }
#pragma unroll
    for (int i = 0; i < 4; ++i) {
      int lr = i * 32 + rq;
      int k16 = s ^ (lr & 7);
      const unsigned short* gsrc = Wt + (size_t)(n0 + lr) * NDIN + kt * 64 + k16 * 8;
      gload16(gsrc, (char*)Bs + i * 4096 + (w << 10));
    }
    __syncthreads();

    s8v af[4][2], bfr[4][2];
#pragma unroll
    for (int mf = 0; mf < 4; ++mf)
#pragma unroll
      for (int ks = 0; ks < 2; ++ks) {
        int row = wm * 64 + mf * 16 + (l & 15);
        int slot = ks * 4 + (l >> 4);
        af[mf][ks] = *(const s8v*)((const char*)As + row * 128 + ((slot ^ (row & 7)) << 4));
      }
#pragma unroll
    for (int nf = 0; nf < 4; ++nf)
#pragma unroll
      for (int ks = 0; ks < 2; ++ks) {
        int row = wn * 64 + nf * 16 + (l & 15);
        int slot = ks * 4 + (l >> 4);
        bfr[nf][ks] = *(const s8v*)((const char*)Bs + row * 128 + ((slot ^ (row & 7)) << 4));
      }
#pragma unroll
    for (int ks = 0; ks < 2; ++ks)
#pragma unroll
      for (int mf = 0; mf < 4; ++mf)
#pragma unroll
        for (int nf = 0; nf < 4; ++nf)
          acc[mf][nf] = __builtin_amdgcn_mfma_f32_16x16x32_bf16(
              af[mf][ks], bfr[nf][ks], acc[mf][nf], 0, 0, 0);
  }

#pragma unroll
  for (int mf = 0; mf < 4; ++mf)
#pragma unroll
    for (int nf = 0; nf < 4; ++nf)
#pragma unroll
      for (int r = 0; r < 4; ++r) {
        int row = m0 + wm * 64 + mf * 16 + (l >> 4) * 4 + r;
        int col = n0 + wn * 64 + nf * 16 + (l & 15);
        out[(size_t)row * NDOUT + col] = acc[mf][nf][r];
      }
}

// ---------------------------------------------------------------------------
extern "C" void kernel_launch(void* const* d_in, const int* in_sizes, int n_in,
                              void* d_out, int out_size, void* d_ws, size_t ws_size,
                              hipStream_t stream) {
  const float* inputs = (const float*)d_in[0];   // (B, C, 16) f32
  const float* cents  = (const float*)d_in[1];   // (C, K, 16) f32
  const float* W      = (const float*)d_in[2];   // (512, 512) f32

  float* out = (float*)d_out;
  float* negout   = out + (size_t)NB * NDOUT;            // (B, C)
  float* codefout = negout + (size_t)NB * NC;            // (B, C) as float

  unsigned short* Wt      = (unsigned short*)d_ws;                          // 512 KiB
  unsigned short* centsH  = (unsigned short*)((char*)d_ws + 512 * 1024);    // 256 KiB
  unsigned short* centsP4 = (unsigned short*)((char*)d_ws + (1 << 20));     // 512 KiB
  float* T_neg            = (float*)((char*)d_ws + 2 * (1 << 20));          // 4 MiB
  int* T_code             = (int*)((char*)d_ws + 6 * (1 << 20));            // 4 MiB

  k_prep<<<288, 256, 0, stream>>>(W, cents, Wt, centsH, centsP4);
  k_score<<<dim3(NB / 256, NC), 256, 0, stream>>>(inputs, centsP4, cents, T_neg, T_code);
  k_gemm<<<dim3(NB / 128, 5), 256, 0, stream>>>(centsH, T_code, T_neg, Wt, out,
                                                negout, codefout);
}